// Round 3
// baseline (15833.018 us; speedup 1.0000x reference)
//
#include <hip/hip_runtime.h>
#include <cstdint>
#include <cstddef>

#define SCOPE_AGENT __HIP_MEMORY_SCOPE_AGENT

namespace {
constexpr int kD = 256;
constexpr int kP0 = 31;
constexpr int kM0 = 496;   // 16 n-seqs * 31 pairs at step 0
}

// ---------------- device state ----------------
__device__ float g_state[2][64 * 32 * 256];    // ping-pong per-b state
__device__ float g_nh[2][64 * kP0 * 256];
__device__ float g_s5[2][64 * kP0 * 5];
__device__ float g_nh0[kM0 * 256];             // step-0 n-indexed
__device__ float g_s50[kM0 * 5];
__device__ float g_inter0[(size_t)kM0 * 1024];
__device__ float g_p1f[4][(size_t)kM0 * 1024]; // step-0 g1 split-K partials
__device__ float g_p2f[8][(size_t)kM0 * 1024]; // step-0 g2 split-K partials
__device__ float g_p1[4][128 * 1024];          // tail g1 partials
__device__ float g_p2[4][128 * 1024];          // tail g2 partials
__device__ float g_accu[64];
__device__ int g_slots[128];
__device__ unsigned g_barLeaf[32];
__device__ unsigned g_barRoot;
__device__ unsigned g_barGen;

// ---------------- grid barrier (256 blocks: 32 leaves x 8) ----------------
__device__ __forceinline__ void gridBar(unsigned gen) {
  __threadfence();            // flush my writes agent-wide
  __syncthreads();            // whole block arrived
  if (threadIdx.x == 0) {
    int leaf = blockIdx.x >> 3;
    if (__hip_atomic_fetch_add(&g_barLeaf[leaf], 1u, __ATOMIC_RELAXED, SCOPE_AGENT) == 7u) {
      __hip_atomic_store(&g_barLeaf[leaf], 0u, __ATOMIC_RELAXED, SCOPE_AGENT);
      if (__hip_atomic_fetch_add(&g_barRoot, 1u, __ATOMIC_RELAXED, SCOPE_AGENT) == 31u) {
        __hip_atomic_store(&g_barRoot, 0u, __ATOMIC_RELAXED, SCOPE_AGENT);
        __hip_atomic_store(&g_barGen, gen, __ATOMIC_RELAXED, SCOPE_AGENT);
      }
    }
    while (__hip_atomic_load(&g_barGen, __ATOMIC_RELAXED, SCOPE_AGENT) < gen)
      __builtin_amdgcn_s_sleep(4);
    __threadfence();          // invalidate L1 before reading others' data
  }
  __syncthreads();
}

// ---------------- threefry2x32 (bit-exact jax, verified passing) ----------------
__device__ __forceinline__ void tf2x32(uint32_t k0, uint32_t k1, uint32_t x0,
                                       uint32_t x1, uint32_t& o0, uint32_t& o1) {
  uint32_t ks2 = k0 ^ k1 ^ 0x1BD11BDAu;
  x0 += k0; x1 += k1;
#define TF_ROT(v, r) (((v) << (r)) | ((v) >> (32 - (r))))
#define TF_RD(r) { x0 += x1; x1 = TF_ROT(x1, r); x1 ^= x0; }
  TF_RD(13) TF_RD(15) TF_RD(26) TF_RD(6)   x0 += k1;  x1 += ks2 + 1u;
  TF_RD(17) TF_RD(29) TF_RD(16) TF_RD(24)  x0 += ks2; x1 += k0 + 2u;
  TF_RD(13) TF_RD(15) TF_RD(26) TF_RD(6)   x0 += k0;  x1 += k1 + 3u;
  TF_RD(17) TF_RD(29) TF_RD(16) TF_RD(24)  x0 += k1;  x1 += ks2 + 4u;
  TF_RD(13) TF_RD(15) TF_RD(26) TF_RD(6)   x0 += ks2; x1 += k0 + 5u;
  o0 = x0; o1 = x1;
#undef TF_RD
#undef TF_ROT
}

__device__ __forceinline__ float waveMax64(float v) {
#pragma unroll
  for (int o = 32; o > 0; o >>= 1) v = fmaxf(v, __shfl_xor(v, o, 64));
  return v;
}
__device__ __forceinline__ float waveSum64(float v) {
#pragma unroll
  for (int o = 32; o > 0; o >>= 1) v += __shfl_xor(v, o, 64);
  return v;
}
__device__ __forceinline__ float geluf(float v) {
  return 0.5f * v * (1.0f + erff(v * 0.70710678118654752440f));
}
// sum of 256 values within a sub-block (4 waves); numerics match round-2 blockSum256
__device__ __forceinline__ float subSum(float v, float* red16, int sub, int st) {
#pragma unroll
  for (int o = 32; o > 0; o >>= 1) v += __shfl_down(v, o, 64);
  __syncthreads();
  if ((st & 63) == 0) red16[sub * 4 + (st >> 6)] = v;
  __syncthreads();
  float* r = red16 + sub * 4;
  return r[0] + r[1] + r[2] + r[3];
}

// ---------------- merge with per-wave redundant Gumbel decision ----------------
__device__ void mergePhase(int i, int gsub, int lane, int wsub,
                           const float* __restrict__ imask,
                           const float* __restrict__ decW,
                           const float* __restrict__ decb) {
  if (gsub >= 512) return;                 // no syncthreads inside: safe skip
  int b = gsub >> 3, jg = gsub & 7;
  int jrow = jg * 4 + wsub;
  int Sc = 31 - i;
  int n32 = (b >> 2) * 32;
  const float* stOld = g_state[i & 1] + b * 8192;
  float* stNew = g_state[(i + 1) & 1] + b * 8192;
  const float* nhSrc = (i == 0) ? (g_nh0 + (size_t)(b >> 2) * kP0 * 256)
                                : (g_nh[i & 1] + (size_t)b * kP0 * 256);
  const float* s5Src = (i == 0) ? (g_s50 + (b >> 2) * kP0 * 5)
                                : (g_s5[i & 1] + b * kP0 * 5);
  float* nhDst = g_nh[(i + 1) & 1] + (size_t)b * kP0 * 256;
  float* s5Dst = g_s5[(i + 1) & 1] + b * kP0 * 5;
  float done = imask[n32 + i + 1];

  // decide (every wave recomputes; deterministic)
  int j = lane;
  bool act = j < Sc;
  float mv = 0.f, lg = 0.f;
  if (act) {
    mv = imask[n32 + i + 1 + j];
    float t5 = decb[0];
    if (j >= 2) t5 += s5Src[(j - 2) * 5 + 0];
    if (j >= 1) t5 += s5Src[(j - 1) * 5 + 1];
    t5 += s5Src[j * 5 + 2];
    if (j + 1 < Sc) t5 += s5Src[(j + 1) * 5 + 3];
    if (j + 2 < Sc) t5 += s5Src[(j + 2) * 5 + 4];
    lg = t5 / 35.77708763999664f;
  }
  uint32_t fk0, fk1, o0, o1;
  tf2x32(0u, 1234u, 0u, (uint32_t)i, fk0, fk1);
  uint32_t idx = (uint32_t)(b * Sc + j);
  tf2x32(fk0, fk1, 0u, idx, o0, o1);
  uint32_t bits = o0 ^ o1;
  float u = __uint_as_float((bits >> 9) | 0x3f800000u) - 1.0f;
  float gum = -logf(-logf(u + 1e-20f) + 1e-20f);
  float z = lg + gum;
  float zm = waveMax64(act ? z : -3.0e38f);
  float e = act ? expf(z - zm) : 0.f;
  float p = e / waveSum64(e);
  float y = act ? (p * mv + 1e-20f) : 0.f;
  float ys = y / waveSum64(y);
  float av = act ? ys : -1.f;
  int ai = j;
#pragma unroll
  for (int o = 32; o > 0; o >>= 1) {
    float ov = __shfl_xor(av, o, 64);
    int oi = __shfl_xor(ai, o, 64);
    if (ov > av || (ov == av && oi < ai)) { av = ov; ai = oi; }
  }
  float lm = waveMax64(act ? lg : -3.0e38f);
  float e2 = act ? expf(lg - lm) : 0.f;
  float p2 = e2 / waveSum64(e2);
  float y2 = act ? (p2 * mv + 1e-20f) : 0.f;
  float ps = y2 / waveSum64(y2);
  float ysk = __shfl(ys, ai, 64);
  float psk = __shfl(ps, ai, 64);
  float sv = (1.0f - ysk) + ysk;
  int k = ai;
  if (jrow == 0 && lane == 0) {
    g_accu[b] += done * logf(sv * psk + 1e-20f);
    int s0 = -1, s1 = -1;
    if (done != 0.0f) {
      if (ai >= 1) s0 = ai - 1;
      if (ai <= Sc - 2) s1 = ai;
    }
    g_slots[2 * b] = s0;
    g_slots[2 * b + 1] = s1;
  }
  if (jrow < Sc) {
    const float* po = stOld + jrow * 256;
    float* pn = stNew + jrow * 256;
    float4 ol = *(const float4*)&po[lane * 4];
    float4 ov4;
    if (done != 0.0f) {
      float4 mg;
      if (jrow < k) {
        mg = ol;
      } else if (jrow == k) {
        float4 nh4 = *(const float4*)&nhSrc[k * 256 + lane * 4];
        mg.x = sv * nh4.x + (1.0f - sv) * ol.x;
        mg.y = sv * nh4.y + (1.0f - sv) * ol.y;
        mg.z = sv * nh4.z + (1.0f - sv) * ol.z;
        mg.w = sv * nh4.w + (1.0f - sv) * ol.w;
      } else {
        float4 orr = *(const float4*)&po[256 + lane * 4];
        mg.x = (1.0f - sv) * ol.x + sv * orr.x;
        mg.y = (1.0f - sv) * ol.y + sv * orr.y;
        mg.z = (1.0f - sv) * ol.z + sv * orr.z;
        mg.w = (1.0f - sv) * ol.w + sv * orr.w;
      }
      ov4.x = done * mg.x + (1.0f - done) * ol.x;
      ov4.y = done * mg.y + (1.0f - done) * ol.y;
      ov4.z = done * mg.z + (1.0f - done) * ol.z;
      ov4.w = done * mg.w + (1.0f - done) * ol.w;
    } else {
      ov4 = ol;
    }
    *(float4*)&pn[lane * 4] = ov4;
    if (jrow < Sc - 1) {
      int src = (done != 0.0f && jrow > k) ? jrow + 1 : jrow;
      float4 nv = *(const float4*)&nhSrc[src * 256 + lane * 4];
      *(float4*)&nhDst[jrow * 256 + lane * 4] = nv;
      float mv2 = imask[n32 + i + 2 + jrow];
      float pv[5];
#pragma unroll
      for (int t = 0; t < 5; ++t) {
        const float* dw = decW + t * 256 + lane * 4;
        pv[t] = (nv.x * dw[0] + nv.y * dw[1] + nv.z * dw[2] + nv.w * dw[3]) * mv2;
      }
#pragma unroll
      for (int t = 0; t < 5; ++t) {
        float v = pv[t];
#pragma unroll
        for (int o = 32; o > 0; o >>= 1) v += __shfl_down(v, o, 64);
        pv[t] = v;
      }
      if (lane == 0) {
#pragma unroll
        for (int t = 0; t < 5; ++t) s5Dst[jrow * 5 + t] = pv[t];
      }
    }
  }
}

__global__ __launch_bounds__(64) void k_init() {
  int t = threadIdx.x;
  if (t < 32) g_barLeaf[t] = 0u;
  if (t == 32) g_barRoot = 0u;
  if (t == 33) g_barGen = 0u;
}

__global__ __launch_bounds__(1024, 4) void k_mega(
    const float* __restrict__ x, const float* __restrict__ imask,
    const float* __restrict__ wW, const float* __restrict__ wb,
    const float* __restrict__ lng, const float* __restrict__ lnb,
    const float* __restrict__ w1, const float* __restrict__ b1,
    const float* __restrict__ w2, const float* __restrict__ b2,
    const float* __restrict__ ln2g, const float* __restrict__ ln2b,
    const float* __restrict__ decW, const float* __restrict__ decb,
    float* __restrict__ out) {
  __shared__ float smem[16384];       // 64KB, 4KB*4sub regions (floats)
  __shared__ float red16[16];
  __shared__ float w5s[4][4][5];
  const int tid = threadIdx.x;
  const int sub = tid >> 8;
  const int st = tid & 255;
  const int lane = tid & 63;
  const int wsub = st >> 6;
  const int gsub = blockIdx.x * 4 + sub;
  unsigned bgen = 0;

  // ================= step 0: embed =================
  {
    float* xs = smem + sub * 4096;
    int row = gsub < 512 ? gsub : 511;
    xs[st] = x[row * 256 + st];
    __syncthreads();
    float acc = wb[st];
    for (int kk = 0; kk < 256; ++kk) acc = fmaf(xs[kk], wW[kk * 256 + st], acc);
    float mean = subSum(acc, red16, sub, st) * (1.0f / 256.0f);
    float cen = acc - mean;
    float var = subSum(cen * cen, red16, sub, st) * (1.0f / 256.0f);
    float o = cen / sqrtf(var + 1e-5f) * lng[st] + lnb[st];
    if (gsub < 512) {
      int n = row >> 5, s = row & 31;
#pragma unroll
      for (int bb = 0; bb < 4; ++bb)
        g_state[0][((n * 4 + bb) * 32 + s) * 256 + st] = o;
    }
    if (gsub == 0 && st < 64) g_accu[st] = 0.0f;
  }
  gridBar(++bgen);

  // ================= step 0: g1full (split-K 4) =================
  {
    int t = gsub & 511;
    int Nt = t & 15, Mt = (t >> 4) & 7, Ks = t >> 7;
    int nBase = Nt * 64, mBase = Mt * 64, kBase = Ks * 128;
    float (*As)[68] = (float (*)[68])(smem + sub * 4096);
    float (*Bs)[64] = (float (*)[64])(smem + sub * 4096 + 1088);
    int ac = st & 15, ar = st >> 4;
    int bc = st & 63, br = st >> 6;
    int tx = st & 15, ty = st >> 4;
    int aoff[4];
#pragma unroll
    for (int s = 0; s < 4; ++s) {
      int row = mBase + ar + s * 16;
      if (row > kM0 - 1) row = kM0 - 1;
      int n = row / 31, jj = row - n * 31;
      aoff[s] = (n * 4) * 8192 + jj * 256;
    }
    float acc[4][4] = {};
    for (int k0 = kBase; k0 < kBase + 128; k0 += 16) {
#pragma unroll
      for (int s = 0; s < 4; ++s) As[ac][ar + s * 16] = g_state[0][aoff[s] + k0 + ac];
#pragma unroll
      for (int s4 = 0; s4 < 4; ++s4)
        Bs[br + s4 * 4][bc] = w1[(size_t)(k0 + br + s4 * 4) * 1024 + nBase + bc];
      __syncthreads();
#pragma unroll
      for (int kk = 0; kk < 16; ++kk) {
        float4 a4 = *(const float4*)&As[kk][ty * 4];
        float4 b4 = *(const float4*)&Bs[kk][tx * 4];
        float avv[4] = {a4.x, a4.y, a4.z, a4.w};
        float bvv[4] = {b4.x, b4.y, b4.z, b4.w};
#pragma unroll
        for (int ii = 0; ii < 4; ++ii)
#pragma unroll
          for (int jj2 = 0; jj2 < 4; ++jj2)
            acc[ii][jj2] = fmaf(avv[ii], bvv[jj2], acc[ii][jj2]);
      }
      __syncthreads();
    }
    if (gsub < 512) {
#pragma unroll
      for (int ii = 0; ii < 4; ++ii) {
        int m = mBase + ty * 4 + ii;
        if (m < kM0) {
#pragma unroll
          for (int jj2 = 0; jj2 < 4; ++jj2)
            g_p1f[Ks][(size_t)m * 1024 + nBase + tx * 4 + jj2] = acc[ii][jj2];
        }
      }
    }
  }
  gridBar(++bgen);

  // ================= step 0: assemble inter = gelu(sum + b1) =================
  {
    for (int e = blockIdx.x * 1024 + tid; e < kM0 * 1024; e += 256 * 1024) {
      int n = e & 1023;
      float v = g_p1f[0][e] + g_p1f[1][e] + g_p1f[2][e] + g_p1f[3][e] + b1[n];
      g_inter0[e] = geluf(v);
    }
  }
  gridBar(++bgen);

  // ================= step 0: g2full (split-K 8) =================
  {
    int Nt = gsub & 15, Mt = (gsub >> 4) & 7, Ks = gsub >> 7;  // Ks 0..7
    int nBase = Nt * 64, mBase = Mt * 64, kBase = Ks * 128;
    float (*As)[68] = (float (*)[68])(smem + sub * 4096);
    float (*Bs)[64] = (float (*)[64])(smem + sub * 4096 + 1088);
    int ac = st & 15, ar = st >> 4;
    int bc = st & 63, br = st >> 6;
    int tx = st & 15, ty = st >> 4;
    int arow[4];
#pragma unroll
    for (int s = 0; s < 4; ++s) {
      int row = mBase + ar + s * 16;
      arow[s] = (row > kM0 - 1) ? (kM0 - 1) : row;
    }
    float acc[4][4] = {};
    for (int k0 = kBase; k0 < kBase + 128; k0 += 16) {
#pragma unroll
      for (int s = 0; s < 4; ++s)
        As[ac][ar + s * 16] = g_inter0[(size_t)arow[s] * 1024 + k0 + ac];
#pragma unroll
      for (int s4 = 0; s4 < 4; ++s4)
        Bs[br + s4 * 4][bc] = w2[(size_t)(k0 + br + s4 * 4) * 1024 + nBase + bc];
      __syncthreads();
#pragma unroll
      for (int kk = 0; kk < 16; ++kk) {
        float4 a4 = *(const float4*)&As[kk][ty * 4];
        float4 b4 = *(const float4*)&Bs[kk][tx * 4];
        float avv[4] = {a4.x, a4.y, a4.z, a4.w};
        float bvv[4] = {b4.x, b4.y, b4.z, b4.w};
#pragma unroll
        for (int ii = 0; ii < 4; ++ii)
#pragma unroll
          for (int jj2 = 0; jj2 < 4; ++jj2)
            acc[ii][jj2] = fmaf(avv[ii], bvv[jj2], acc[ii][jj2]);
      }
      __syncthreads();
    }
#pragma unroll
    for (int ii = 0; ii < 4; ++ii) {
      int m = mBase + ty * 4 + ii;
      if (m < kM0) {
#pragma unroll
        for (int jj2 = 0; jj2 < 4; ++jj2)
          g_p2f[Ks][(size_t)m * 1024 + nBase + tx * 4 + jj2] = acc[ii][jj2];
      }
    }
  }
  gridBar(++bgen);

  // ================= step 0: cellfull =================
  {
    bool act = gsub < kM0;
    int m = act ? gsub : kM0 - 1;
    int n = m / 31, j = m - n * 31;
    float c[4];
#pragma unroll
    for (int q = 0; q < 4; ++q) {
      size_t g = (size_t)m * 1024 + q * 256 + st;
      float v = g_p2f[0][g];
#pragma unroll
      for (int ks = 1; ks < 8; ++ks) v += g_p2f[ks][g];
      c[q] = v + b2[q * 256 + st];
    }
    const float* stp = g_state[0] + (n * 4) * 8192;
    float l = stp[j * 256 + st];
    float r = stp[(j + 1) * 256 + st];
    float f1 = 1.0f / (1.0f + expf(-c[0]));
    float f2 = 1.0f / (1.0f + expf(-c[1]));
    float ig = 1.0f / (1.0f + expf(-c[2]));
    float pre = f1 * l + f2 * r + ig * c[3];
    float mean = subSum(pre, red16, sub, st) * (1.0f / 256.0f);
    float cen = pre - mean;
    float var = subSum(cen * cen, red16, sub, st) * (1.0f / 256.0f);
    float nh = cen / sqrtf(var + 1e-5f) * ln2g[st] + ln2b[st];
    if (act) g_nh0[m * 256 + st] = nh;
    float mv = imask[n * 32 + 1 + j];
    float nhm = nh * mv;
    float pv[5];
#pragma unroll
    for (int t = 0; t < 5; ++t) pv[t] = nhm * decW[t * 256 + st];
#pragma unroll
    for (int t = 0; t < 5; ++t) {
      float v = pv[t];
#pragma unroll
      for (int o = 32; o > 0; o >>= 1) v += __shfl_down(v, o, 64);
      pv[t] = v;
    }
    __syncthreads();
    if (lane == 0) {
#pragma unroll
      for (int t = 0; t < 5; ++t) w5s[sub][wsub][t] = pv[t];
    }
    __syncthreads();
    if (st < 5 && act)
      g_s50[m * 5 + st] = w5s[sub][0][st] + w5s[sub][1][st] + w5s[sub][2][st] + w5s[sub][3][st];
  }
  gridBar(++bgen);

  // ================= step 0: merge =================
  mergePhase(0, gsub, lane, wsub, imask, decW, decb);
  gridBar(++bgen);

  // ================= steps 1..30 =================
#pragma unroll 1
  for (int i = 1; i <= 30; ++i) {
    int buf = i & 1;

    // ---- g1inc: 128 slot rows, split-K 4 ----
    {
      int t = gsub & 511;
      int ct = t & 15, rg = (t >> 4) & 7, Ks = t >> 7;
      int kBase = Ks * 128, col0 = ct * 64;
      float* As = smem + sub * 4096;   // [16][128]
      {
        int srow = rg * 16 + (st >> 4);
        int bq = srow >> 1;
        int jq = g_slots[srow];
        if (jq < 0) jq = 0;
        const float* Ar = g_state[buf] + bq * 8192 + jq * 256 + kBase + (st & 15) * 8;
        float4 v0 = *(const float4*)&Ar[0];
        float4 v1 = *(const float4*)&Ar[4];
        float* dst = As + (st >> 4) * 128 + (st & 15) * 8;
        *(float4*)&dst[0] = v0;
        *(float4*)&dst[4] = v1;
      }
      __syncthreads();
      int r16 = st >> 4, c4 = st & 15;
      float a0 = 0.f, a1 = 0.f, a2 = 0.f, a3 = 0.f;
      for (int kk = 0; kk < 128; ++kk) {
        float a = As[r16 * 128 + kk];
        float4 w = *(const float4*)&w1[(size_t)(kBase + kk) * 1024 + col0 + c4 * 4];
        a0 = fmaf(a, w.x, a0); a1 = fmaf(a, w.y, a1);
        a2 = fmaf(a, w.z, a2); a3 = fmaf(a, w.w, a3);
      }
      __syncthreads();
      if (gsub < 512) {
        int orow = rg * 16 + r16;
        float4 o4 = {a0, a1, a2, a3};
        *(float4*)&g_p1[Ks][orow * 1024 + col0 + c4 * 4] = o4;
      }
    }
    gridBar(++bgen);

    // ---- g2inc: split-K 4 (256 each), gelu-assembly inlined ----
    {
      int t = gsub & 511;
      int ct = t & 15, rg = (t >> 4) & 7, Ks = t >> 7;
      int kBase = Ks * 256, col0 = ct * 64;
      float* As = smem + sub * 4096;   // [16][256]
#pragma unroll
      for (int q4 = 0; q4 < 4; ++q4) {
        int e0 = st * 16 + q4 * 4;
        int row = e0 >> 8, kk = e0 & 255;
        int orow = rg * 16 + row;
        int g = orow * 1024 + kBase + kk;
        float4 p0 = *(const float4*)&g_p1[0][g];
        float4 p1v = *(const float4*)&g_p1[1][g];
        float4 p2v = *(const float4*)&g_p1[2][g];
        float4 p3v = *(const float4*)&g_p1[3][g];
        float4 bb = *(const float4*)&b1[kBase + kk];
        float4 r_;
        r_.x = geluf(p0.x + p1v.x + p2v.x + p3v.x + bb.x);
        r_.y = geluf(p0.y + p1v.y + p2v.y + p3v.y + bb.y);
        r_.z = geluf(p0.z + p1v.z + p2v.z + p3v.z + bb.z);
        r_.w = geluf(p0.w + p1v.w + p2v.w + p3v.w + bb.w);
        *(float4*)&As[e0] = r_;
      }
      __syncthreads();
      int r16 = st >> 4, c4 = st & 15;
      float a0 = 0.f, a1 = 0.f, a2 = 0.f, a3 = 0.f;
      for (int kk = 0; kk < 256; ++kk) {
        float a = As[r16 * 256 + kk];
        float4 w = *(const float4*)&w2[(size_t)(kBase + kk) * 1024 + col0 + c4 * 4];
        a0 = fmaf(a, w.x, a0); a1 = fmaf(a, w.y, a1);
        a2 = fmaf(a, w.z, a2); a3 = fmaf(a, w.w, a3);
      }
      __syncthreads();
      if (gsub < 512) {
        int orow = rg * 16 + r16;
        float4 o4 = {a0, a1, a2, a3};
        *(float4*)&g_p2[Ks][orow * 1024 + col0 + c4 * 4] = o4;
      }
    }
    gridBar(++bgen);

    // ---- cellinc: 128 slot rows ----
    {
      bool act = gsub < 128;
      int s = act ? gsub : 127;
      int b = s >> 1;
      int j = g_slots[s];
      bool ok = act && (j >= 0);
      int jc = j >= 0 ? j : 0;
      float c[4];
#pragma unroll
      for (int q = 0; q < 4; ++q) {
        int g = s * 1024 + q * 256 + st;
        float v = ((g_p2[0][g] + g_p2[1][g]) + g_p2[2][g]) + g_p2[3][g];
        c[q] = v + b2[q * 256 + st];
      }
      const float* stp = g_state[buf] + b * 8192;
      float l = stp[jc * 256 + st];
      float r = stp[(jc + 1) * 256 + st];
      float f1 = 1.0f / (1.0f + expf(-c[0]));
      float f2 = 1.0f / (1.0f + expf(-c[1]));
      float ig = 1.0f / (1.0f + expf(-c[2]));
      float pre = f1 * l + f2 * r + ig * c[3];
      float mean = subSum(pre, red16, sub, st) * (1.0f / 256.0f);
      float cen = pre - mean;
      float var = subSum(cen * cen, red16, sub, st) * (1.0f / 256.0f);
      float nh = cen / sqrtf(var + 1e-5f) * ln2g[st] + ln2b[st];
      if (ok) g_nh[buf][((size_t)b * kP0 + jc) * 256 + st] = nh;
      float mv = imask[(b >> 2) * 32 + i + 1 + jc];
      float nhm = nh * mv;
      float pv[5];
#pragma unroll
      for (int t = 0; t < 5; ++t) pv[t] = nhm * decW[t * 256 + st];
#pragma unroll
      for (int t = 0; t < 5; ++t) {
        float v = pv[t];
#pragma unroll
        for (int o = 32; o > 0; o >>= 1) v += __shfl_down(v, o, 64);
        pv[t] = v;
      }
      __syncthreads();
      if (lane == 0) {
#pragma unroll
        for (int t = 0; t < 5; ++t) w5s[sub][wsub][t] = pv[t];
      }
      __syncthreads();
      if (st < 5 && ok)
        g_s5[buf][((size_t)b * kP0 + jc) * 5 + st] =
            w5s[sub][0][st] + w5s[sub][1][st] + w5s[sub][2][st] + w5s[sub][3][st];
    }
    gridBar(++bgen);

    // ---- merge / mergelast ----
    if (i < 30) {
      mergePhase(i, gsub, lane, wsub, imask, decW, decb);
    } else {
      if (gsub < 64 && wsub == 0) {
        int b = gsub;
        float done = imask[(b >> 2) * 32 + 31];
        const float* stOld = g_state[0] + b * 8192;
        float* stNew = g_state[1] + b * 8192;
        float4 nh4 = *(const float4*)&g_nh[0][(size_t)b * kP0 * 256 + lane * 4];
        float4 ol = *(const float4*)&stOld[lane * 4];
        float4 o4;
        o4.x = done * nh4.x + (1.0f - done) * ol.x;
        o4.y = done * nh4.y + (1.0f - done) * ol.y;
        o4.z = done * nh4.z + (1.0f - done) * ol.z;
        o4.w = done * nh4.w + (1.0f - done) * ol.w;
        *(float4*)&stNew[lane * 4] = o4;
      }
    }
    gridBar(++bgen);
  }

  // ================= final =================
  if (gsub < 16 && wsub == 0) {
    int n = gsub;
    float a0 = g_accu[n * 4 + 0], a1 = g_accu[n * 4 + 1];
    float a2 = g_accu[n * 4 + 2], a3 = g_accu[n * 4 + 3];
    float mx = fmaxf(fmaxf(a0, a1), fmaxf(a2, a3));
    float e0 = expf(a0 - mx), e1 = expf(a1 - mx);
    float e2 = expf(a2 - mx), e3 = expf(a3 - mx);
    float ssum = e0 + e1 + e2 + e3;
    const float* st1 = g_state[1];
    float4 h0 = *(const float4*)&st1[(n * 4 + 0) * 8192 + lane * 4];
    float4 h1 = *(const float4*)&st1[(n * 4 + 1) * 8192 + lane * 4];
    float4 h2 = *(const float4*)&st1[(n * 4 + 2) * 8192 + lane * 4];
    float4 h3 = *(const float4*)&st1[(n * 4 + 3) * 8192 + lane * 4];
    float4 o4;
    o4.x = (e0 / ssum) * h0.x + (e1 / ssum) * h1.x + (e2 / ssum) * h2.x + (e3 / ssum) * h3.x;
    o4.y = (e0 / ssum) * h0.y + (e1 / ssum) * h1.y + (e2 / ssum) * h2.y + (e3 / ssum) * h3.y;
    o4.z = (e0 / ssum) * h0.z + (e1 / ssum) * h1.z + (e2 / ssum) * h2.z + (e3 / ssum) * h3.z;
    o4.w = (e0 / ssum) * h0.w + (e1 / ssum) * h1.w + (e2 / ssum) * h2.w + (e3 / ssum) * h3.w;
    *(float4*)&out[n * 256 + lane * 4] = o4;
  }
}

extern "C" void kernel_launch(void* const* d_in, const int* in_sizes, int n_in,
                              void* d_out, int out_size, void* d_ws, size_t ws_size,
                              hipStream_t stream) {
  (void)in_sizes; (void)n_in; (void)d_ws; (void)ws_size; (void)out_size;
  const float* x = (const float*)d_in[0];
  const float* imask = (const float*)d_in[1];
  const float* wW = (const float*)d_in[2];
  const float* wb = (const float*)d_in[3];
  const float* lng = (const float*)d_in[4];
  const float* lnb = (const float*)d_in[5];
  const float* w1 = (const float*)d_in[6];
  const float* b1 = (const float*)d_in[7];
  const float* w2 = (const float*)d_in[8];
  const float* b2 = (const float*)d_in[9];
  const float* ln2g = (const float*)d_in[10];
  const float* ln2b = (const float*)d_in[11];
  const float* decW = (const float*)d_in[12];
  const float* decb = (const float*)d_in[13];
  float* out = (float*)d_out;

  k_init<<<dim3(1), dim3(64), 0, stream>>>();
  k_mega<<<dim3(256), dim3(1024), 0, stream>>>(x, imask, wW, wb, lng, lnb, w1, b1,
                                               w2, b2, ln2g, ln2b, decW, decb, out);
}

// Round 4
// 1313.662 us; speedup vs baseline: 12.0526x; 12.0526x over previous
//
#include <hip/hip_runtime.h>
#include <cstdint>
#include <cstddef>

namespace {
constexpr int kP0 = 31;
constexpr int kM0 = 496;   // 16 n-seqs * 31 pairs at step 0
}

// ---------------- device state ----------------
__device__ float g_state[2][64 * 32 * 256];     // ping-pong per-b state
__device__ float g_nh[2][64 * kP0 * 256];       // pair-row cell outputs (b-indexed)
__device__ float g_s5[2][64 * kP0 * 5];
__device__ float g_nh0[kM0 * 256];              // step-0 n-indexed
__device__ float g_s50[kM0 * 5];
__device__ float g_inter0[(size_t)kM0 * 1024];
__device__ float g_cont0[(size_t)kM0 * 1024];
__device__ float g_p1[4][128 * 1024];           // tail g1 split-K partials
__device__ float g_p2[4][128 * 1024];           // tail g2 split-K partials
__device__ float g_accu[64];
__device__ int g_slots[2][128];                 // parity-buffered fresh-row indices

// ---------------- threefry2x32 (bit-exact jax, verified passing) ----------------
__device__ __forceinline__ void tf2x32(uint32_t k0, uint32_t k1, uint32_t x0,
                                       uint32_t x1, uint32_t& o0, uint32_t& o1) {
  uint32_t ks2 = k0 ^ k1 ^ 0x1BD11BDAu;
  x0 += k0; x1 += k1;
#define TF_ROT(v, r) (((v) << (r)) | ((v) >> (32 - (r))))
#define TF_RD(r) { x0 += x1; x1 = TF_ROT(x1, r); x1 ^= x0; }
  TF_RD(13) TF_RD(15) TF_RD(26) TF_RD(6)   x0 += k1;  x1 += ks2 + 1u;
  TF_RD(17) TF_RD(29) TF_RD(16) TF_RD(24)  x0 += ks2; x1 += k0 + 2u;
  TF_RD(13) TF_RD(15) TF_RD(26) TF_RD(6)   x0 += k0;  x1 += k1 + 3u;
  TF_RD(17) TF_RD(29) TF_RD(16) TF_RD(24)  x0 += k1;  x1 += ks2 + 4u;
  TF_RD(13) TF_RD(15) TF_RD(26) TF_RD(6)   x0 += ks2; x1 += k0 + 5u;
  o0 = x0; o1 = x1;
#undef TF_RD
#undef TF_ROT
}

__device__ __forceinline__ float blockSum256(float v, float* red4, int tid) {
#pragma unroll
  for (int o = 32; o > 0; o >>= 1) v += __shfl_down(v, o, 64);
  __syncthreads();
  if ((tid & 63) == 0) red4[tid >> 6] = v;
  __syncthreads();
  return red4[0] + red4[1] + red4[2] + red4[3];
}
__device__ __forceinline__ float waveMax64(float v) {
#pragma unroll
  for (int o = 32; o > 0; o >>= 1) v = fmaxf(v, __shfl_xor(v, o, 64));
  return v;
}
__device__ __forceinline__ float waveSum64(float v) {
#pragma unroll
  for (int o = 32; o > 0; o >>= 1) v += __shfl_xor(v, o, 64);
  return v;
}
__device__ __forceinline__ float geluf(float v) {
  return 0.5f * v * (1.0f + erff(v * 0.70710678118654752440f));
}

// ---------------- embed + LN, replicate to B copies ----------------
__global__ __launch_bounds__(256) void k_embed(const float* __restrict__ x,
                                               const float* __restrict__ wW,
                                               const float* __restrict__ wb,
                                               const float* __restrict__ lng,
                                               const float* __restrict__ lnb) {
  int row = blockIdx.x;  // n*32 + s
  int d = threadIdx.x;
  __shared__ float xs[256];
  __shared__ float red4[4];
  xs[d] = x[row * 256 + d];
  __syncthreads();
  float acc = wb[d];
  for (int k = 0; k < 256; ++k) acc = fmaf(xs[k], wW[k * 256 + d], acc);
  float mean = blockSum256(acc, red4, d) * (1.0f / 256.0f);
  float cen = acc - mean;
  float var = blockSum256(cen * cen, red4, d) * (1.0f / 256.0f);
  float o = cen / sqrtf(var + 1e-5f) * lng[d] + lnb[d];
  int n = row >> 5, s = row & 31;
#pragma unroll
  for (int bb = 0; bb < 4; ++bb)
    g_state[0][((n * 4 + bb) * 32 + s) * 256 + d] = o;
  if (row == 0 && d < 64) g_accu[d] = 0.0f;
}

// =============== GEMM kernels: 32-row x 64-col tiles, reg-dbuf K-chunks of 64 ===============

// step-0 g1: inter0 = gelu(state_rows @ w1 + b1), K=512 sequential
__global__ __launch_bounds__(256) void k_g1s(const float* __restrict__ w1,
                                             const float* __restrict__ b1) {
  __shared__ float As[64][33];
  __shared__ float Ws[64][68];
  const int tid = threadIdx.x;
  const int colB = blockIdx.x * 64;
  const int rowB = blockIdx.y * 32;
  const int row = tid & 15, cg = tid >> 4;
  const int ar = tid >> 4, ak = (tid & 15) * 4;
  const float *Ab0, *Ab1;
  {
    int m0 = rowB + ar; if (m0 > kM0 - 1) m0 = kM0 - 1;
    int m1 = rowB + ar + 16; if (m1 > kM0 - 1) m1 = kM0 - 1;
    int n0 = m0 / 31, j0 = m0 - n0 * 31;
    int n1 = m1 / 31, j1 = m1 - n1 * 31;
    Ab0 = g_state[0] + (n0 * 4) * 8192 + j0 * 256;
    Ab1 = g_state[0] + (n1 * 4) * 8192 + j1 * 256;
  }
  float4 aR0 = *(const float4*)&Ab0[ak];
  float4 aR1 = *(const float4*)&Ab1[ak];
  float4 wR[4];
#pragma unroll
  for (int q = 0; q < 4; ++q) {
    int f = tid + q * 256; int kk = f >> 4, c4 = f & 15;
    wR[q] = *(const float4*)&w1[(size_t)kk * 1024 + colB + c4 * 4];
  }
  float acc0[4] = {}, acc1[4] = {};
  for (int c = 0; c < 8; ++c) {
    As[ak + 0][ar] = aR0.x; As[ak + 1][ar] = aR0.y; As[ak + 2][ar] = aR0.z; As[ak + 3][ar] = aR0.w;
    As[ak + 0][ar + 16] = aR1.x; As[ak + 1][ar + 16] = aR1.y; As[ak + 2][ar + 16] = aR1.z; As[ak + 3][ar + 16] = aR1.w;
#pragma unroll
    for (int q = 0; q < 4; ++q) {
      int f = tid + q * 256; int kk = f >> 4, c4 = f & 15;
      *(float4*)&Ws[kk][c4 * 4] = wR[q];
    }
    __syncthreads();
    if (c < 7) {
      int kb = (c + 1) * 64;
      aR0 = *(const float4*)&Ab0[kb + ak];
      aR1 = *(const float4*)&Ab1[kb + ak];
#pragma unroll
      for (int q = 0; q < 4; ++q) {
        int f = tid + q * 256; int kk = f >> 4, c4 = f & 15;
        wR[q] = *(const float4*)&w1[(size_t)(kb + kk) * 1024 + colB + c4 * 4];
      }
    }
#pragma unroll
    for (int kk = 0; kk < 64; ++kk) {
      float a0 = As[kk][row], a1 = As[kk][row + 16];
      float4 w = *(const float4*)&Ws[kk][cg * 4];
      acc0[0] = fmaf(a0, w.x, acc0[0]); acc0[1] = fmaf(a0, w.y, acc0[1]);
      acc0[2] = fmaf(a0, w.z, acc0[2]); acc0[3] = fmaf(a0, w.w, acc0[3]);
      acc1[0] = fmaf(a1, w.x, acc1[0]); acc1[1] = fmaf(a1, w.y, acc1[1]);
      acc1[2] = fmaf(a1, w.z, acc1[2]); acc1[3] = fmaf(a1, w.w, acc1[3]);
    }
    __syncthreads();
  }
  int col = colB + cg * 4;
  float4 bb = *(const float4*)&b1[col];
  int m0 = rowB + row, m1 = rowB + row + 16;
  if (m0 < kM0) {
    float4 o;
    o.x = geluf(acc0[0] + bb.x); o.y = geluf(acc0[1] + bb.y);
    o.z = geluf(acc0[2] + bb.z); o.w = geluf(acc0[3] + bb.w);
    *(float4*)&g_inter0[(size_t)m0 * 1024 + col] = o;
  }
  if (m1 < kM0) {
    float4 o;
    o.x = geluf(acc1[0] + bb.x); o.y = geluf(acc1[1] + bb.y);
    o.z = geluf(acc1[2] + bb.z); o.w = geluf(acc1[3] + bb.w);
    *(float4*)&g_inter0[(size_t)m1 * 1024 + col] = o;
  }
}

// step-0 g2: cont0 = inter0 @ w2 (raw; b2 added in cellfull), K=1024 sequential
__global__ __launch_bounds__(256) void k_g2s(const float* __restrict__ w2) {
  __shared__ float As[64][33];
  __shared__ float Ws[64][68];
  const int tid = threadIdx.x;
  const int colB = blockIdx.x * 64;
  const int rowB = blockIdx.y * 32;
  const int row = tid & 15, cg = tid >> 4;
  const int ar = tid >> 4, ak = (tid & 15) * 4;
  int m0s = rowB + ar; if (m0s > kM0 - 1) m0s = kM0 - 1;
  int m1s = rowB + ar + 16; if (m1s > kM0 - 1) m1s = kM0 - 1;
  const float* Ab0 = g_inter0 + (size_t)m0s * 1024;
  const float* Ab1 = g_inter0 + (size_t)m1s * 1024;
  float4 aR0 = *(const float4*)&Ab0[ak];
  float4 aR1 = *(const float4*)&Ab1[ak];
  float4 wR[4];
#pragma unroll
  for (int q = 0; q < 4; ++q) {
    int f = tid + q * 256; int kk = f >> 4, c4 = f & 15;
    wR[q] = *(const float4*)&w2[(size_t)kk * 1024 + colB + c4 * 4];
  }
  float acc0[4] = {}, acc1[4] = {};
  for (int c = 0; c < 16; ++c) {
    As[ak + 0][ar] = aR0.x; As[ak + 1][ar] = aR0.y; As[ak + 2][ar] = aR0.z; As[ak + 3][ar] = aR0.w;
    As[ak + 0][ar + 16] = aR1.x; As[ak + 1][ar + 16] = aR1.y; As[ak + 2][ar + 16] = aR1.z; As[ak + 3][ar + 16] = aR1.w;
#pragma unroll
    for (int q = 0; q < 4; ++q) {
      int f = tid + q * 256; int kk = f >> 4, c4 = f & 15;
      *(float4*)&Ws[kk][c4 * 4] = wR[q];
    }
    __syncthreads();
    if (c < 15) {
      int kb = (c + 1) * 64;
      aR0 = *(const float4*)&Ab0[kb + ak];
      aR1 = *(const float4*)&Ab1[kb + ak];
#pragma unroll
      for (int q = 0; q < 4; ++q) {
        int f = tid + q * 256; int kk = f >> 4, c4 = f & 15;
        wR[q] = *(const float4*)&w2[(size_t)(kb + kk) * 1024 + colB + c4 * 4];
      }
    }
#pragma unroll
    for (int kk = 0; kk < 64; ++kk) {
      float a0 = As[kk][row], a1 = As[kk][row + 16];
      float4 w = *(const float4*)&Ws[kk][cg * 4];
      acc0[0] = fmaf(a0, w.x, acc0[0]); acc0[1] = fmaf(a0, w.y, acc0[1]);
      acc0[2] = fmaf(a0, w.z, acc0[2]); acc0[3] = fmaf(a0, w.w, acc0[3]);
      acc1[0] = fmaf(a1, w.x, acc1[0]); acc1[1] = fmaf(a1, w.y, acc1[1]);
      acc1[2] = fmaf(a1, w.z, acc1[2]); acc1[3] = fmaf(a1, w.w, acc1[3]);
    }
    __syncthreads();
  }
  int col = colB + cg * 4;
  int m0 = rowB + row, m1 = rowB + row + 16;
  if (m0 < kM0) {
    float4 o = {acc0[0], acc0[1], acc0[2], acc0[3]};
    *(float4*)&g_cont0[(size_t)m0 * 1024 + col] = o;
  }
  if (m1 < kM0) {
    float4 o = {acc1[0], acc1[1], acc1[2], acc1[3]};
    *(float4*)&g_cont0[(size_t)m1 * 1024 + col] = o;
  }
}

// tail g1: partials over K-range [Ks*128, Ks*128+128), 128 slot rows
__global__ __launch_bounds__(256) void k_g1t(const float* __restrict__ w1, int buf) {
  __shared__ float As[64][33];
  __shared__ float Ws[64][68];
  const int tid = threadIdx.x;
  const int colB = blockIdx.x * 64;
  const int rowB = blockIdx.y * 32;
  const int Ks = blockIdx.z;
  const int kb0 = Ks * 128;
  const int row = tid & 15, cg = tid >> 4;
  const int ar = tid >> 4, ak = (tid & 15) * 4;
  const float *Ab0, *Ab1;
  {
    int s0 = rowB + ar, s1 = rowB + ar + 16;
    int j0 = g_slots[buf][s0]; if (j0 < 0) j0 = 0;
    int j1 = g_slots[buf][s1]; if (j1 < 0) j1 = 0;
    Ab0 = g_state[buf] + (s0 >> 1) * 8192 + j0 * 256;
    Ab1 = g_state[buf] + (s1 >> 1) * 8192 + j1 * 256;
  }
  float4 aR0 = *(const float4*)&Ab0[kb0 + ak];
  float4 aR1 = *(const float4*)&Ab1[kb0 + ak];
  float4 wR[4];
#pragma unroll
  for (int q = 0; q < 4; ++q) {
    int f = tid + q * 256; int kk = f >> 4, c4 = f & 15;
    wR[q] = *(const float4*)&w1[(size_t)(kb0 + kk) * 1024 + colB + c4 * 4];
  }
  float acc0[4] = {}, acc1[4] = {};
  for (int c = 0; c < 2; ++c) {
    As[ak + 0][ar] = aR0.x; As[ak + 1][ar] = aR0.y; As[ak + 2][ar] = aR0.z; As[ak + 3][ar] = aR0.w;
    As[ak + 0][ar + 16] = aR1.x; As[ak + 1][ar + 16] = aR1.y; As[ak + 2][ar + 16] = aR1.z; As[ak + 3][ar + 16] = aR1.w;
#pragma unroll
    for (int q = 0; q < 4; ++q) {
      int f = tid + q * 256; int kk = f >> 4, c4 = f & 15;
      *(float4*)&Ws[kk][c4 * 4] = wR[q];
    }
    __syncthreads();
    if (c < 1) {
      int kb = kb0 + 64;
      aR0 = *(const float4*)&Ab0[kb + ak];
      aR1 = *(const float4*)&Ab1[kb + ak];
#pragma unroll
      for (int q = 0; q < 4; ++q) {
        int f = tid + q * 256; int kk = f >> 4, c4 = f & 15;
        wR[q] = *(const float4*)&w1[(size_t)(kb + kk) * 1024 + colB + c4 * 4];
      }
    }
#pragma unroll
    for (int kk = 0; kk < 64; ++kk) {
      float a0 = As[kk][row], a1 = As[kk][row + 16];
      float4 w = *(const float4*)&Ws[kk][cg * 4];
      acc0[0] = fmaf(a0, w.x, acc0[0]); acc0[1] = fmaf(a0, w.y, acc0[1]);
      acc0[2] = fmaf(a0, w.z, acc0[2]); acc0[3] = fmaf(a0, w.w, acc0[3]);
      acc1[0] = fmaf(a1, w.x, acc1[0]); acc1[1] = fmaf(a1, w.y, acc1[1]);
      acc1[2] = fmaf(a1, w.z, acc1[2]); acc1[3] = fmaf(a1, w.w, acc1[3]);
    }
    __syncthreads();
  }
  int col = colB + cg * 4;
  {
    float4 o = {acc0[0], acc0[1], acc0[2], acc0[3]};
    *(float4*)&g_p1[Ks][(rowB + row) * 1024 + col] = o;
  }
  {
    float4 o = {acc1[0], acc1[1], acc1[2], acc1[3]};
    *(float4*)&g_p1[Ks][(rowB + row + 16) * 1024 + col] = o;
  }
}

// tail g2: partials over K-range [Ks*256, +256); A assembled as gelu(sum(p1)+b1)
__device__ __forceinline__ float4 g2t_loadA(int grow, int kpos, const float* __restrict__ b1) {
  size_t g = (size_t)grow * 1024 + kpos;
  float4 p0 = *(const float4*)&g_p1[0][g];
  float4 p1 = *(const float4*)&g_p1[1][g];
  float4 p2 = *(const float4*)&g_p1[2][g];
  float4 p3 = *(const float4*)&g_p1[3][g];
  float4 bb = *(const float4*)&b1[kpos];
  float4 r;
  r.x = geluf(p0.x + p1.x + p2.x + p3.x + bb.x);
  r.y = geluf(p0.y + p1.y + p2.y + p3.y + bb.y);
  r.z = geluf(p0.z + p1.z + p2.z + p3.z + bb.z);
  r.w = geluf(p0.w + p1.w + p2.w + p3.w + bb.w);
  return r;
}

__global__ __launch_bounds__(256) void k_g2t(const float* __restrict__ w2,
                                             const float* __restrict__ b1) {
  __shared__ float As[64][33];
  __shared__ float Ws[64][68];
  const int tid = threadIdx.x;
  const int colB = blockIdx.x * 64;
  const int rowB = blockIdx.y * 32;
  const int Ks = blockIdx.z;
  const int kb0 = Ks * 256;
  const int row = tid & 15, cg = tid >> 4;
  const int ar = tid >> 4, ak = (tid & 15) * 4;
  const int grow0 = rowB + ar, grow1 = rowB + ar + 16;
  float4 aR0 = g2t_loadA(grow0, kb0 + ak, b1);
  float4 aR1 = g2t_loadA(grow1, kb0 + ak, b1);
  float4 wR[4];
#pragma unroll
  for (int q = 0; q < 4; ++q) {
    int f = tid + q * 256; int kk = f >> 4, c4 = f & 15;
    wR[q] = *(const float4*)&w2[(size_t)(kb0 + kk) * 1024 + colB + c4 * 4];
  }
  float acc0[4] = {}, acc1[4] = {};
  for (int c = 0; c < 4; ++c) {
    As[ak + 0][ar] = aR0.x; As[ak + 1][ar] = aR0.y; As[ak + 2][ar] = aR0.z; As[ak + 3][ar] = aR0.w;
    As[ak + 0][ar + 16] = aR1.x; As[ak + 1][ar + 16] = aR1.y; As[ak + 2][ar + 16] = aR1.z; As[ak + 3][ar + 16] = aR1.w;
#pragma unroll
    for (int q = 0; q < 4; ++q) {
      int f = tid + q * 256; int kk = f >> 4, c4 = f & 15;
      *(float4*)&Ws[kk][c4 * 4] = wR[q];
    }
    __syncthreads();
    if (c < 3) {
      int kb = kb0 + (c + 1) * 64;
      aR0 = g2t_loadA(grow0, kb + ak, b1);
      aR1 = g2t_loadA(grow1, kb + ak, b1);
#pragma unroll
      for (int q = 0; q < 4; ++q) {
        int f = tid + q * 256; int kk = f >> 4, c4 = f & 15;
        wR[q] = *(const float4*)&w2[(size_t)(kb + kk) * 1024 + colB + c4 * 4];
      }
    }
#pragma unroll
    for (int kk = 0; kk < 64; ++kk) {
      float a0 = As[kk][row], a1 = As[kk][row + 16];
      float4 w = *(const float4*)&Ws[kk][cg * 4];
      acc0[0] = fmaf(a0, w.x, acc0[0]); acc0[1] = fmaf(a0, w.y, acc0[1]);
      acc0[2] = fmaf(a0, w.z, acc0[2]); acc0[3] = fmaf(a0, w.w, acc0[3]);
      acc1[0] = fmaf(a1, w.x, acc1[0]); acc1[1] = fmaf(a1, w.y, acc1[1]);
      acc1[2] = fmaf(a1, w.z, acc1[2]); acc1[3] = fmaf(a1, w.w, acc1[3]);
    }
    __syncthreads();
  }
  int col = colB + cg * 4;
  {
    float4 o = {acc0[0], acc0[1], acc0[2], acc0[3]};
    *(float4*)&g_p2[Ks][(rowB + row) * 1024 + col] = o;
  }
  {
    float4 o = {acc1[0], acc1[1], acc1[2], acc1[3]};
    *(float4*)&g_p2[Ks][(rowB + row + 16) * 1024 + col] = o;
  }
}

// ---------------- step-0 cell (all 496 rows) ----------------
__global__ __launch_bounds__(256) void k_cellfull(const float* __restrict__ imask,
                                                  const float* __restrict__ ln2g,
                                                  const float* __restrict__ ln2b,
                                                  const float* __restrict__ decW,
                                                  const float* __restrict__ b2) {
  int m = blockIdx.x;    // n*31 + j
  int d = threadIdx.x;
  int n = m / 31, j = m - n * 31;
  const float* st = g_state[0] + (n * 4) * 8192;
  const float* crow = g_cont0 + (size_t)m * 1024;
  float c0 = crow[d] + b2[d];
  float c1 = crow[256 + d] + b2[256 + d];
  float c2 = crow[512 + d] + b2[512 + d];
  float c3 = crow[768 + d] + b2[768 + d];
  float l = st[j * 256 + d];
  float r = st[(j + 1) * 256 + d];
  float f1 = 1.0f / (1.0f + expf(-c0));
  float f2 = 1.0f / (1.0f + expf(-c1));
  float ig = 1.0f / (1.0f + expf(-c2));
  float pre = f1 * l + f2 * r + ig * c3;
  __shared__ float red4[4];
  __shared__ float w5[4][5];
  float mean = blockSum256(pre, red4, d) * (1.0f / 256.0f);
  float cen = pre - mean;
  float var = blockSum256(cen * cen, red4, d) * (1.0f / 256.0f);
  float nh = cen / sqrtf(var + 1e-5f) * ln2g[d] + ln2b[d];
  g_nh0[m * 256 + d] = nh;
  float mv = imask[n * 32 + 1 + j];
  float nhm = nh * mv;
  float pv[5];
#pragma unroll
  for (int t = 0; t < 5; ++t) pv[t] = nhm * decW[t * 256 + d];
#pragma unroll
  for (int t = 0; t < 5; ++t)
#pragma unroll
    for (int o = 32; o > 0; o >>= 1) pv[t] += __shfl_down(pv[t], o, 64);
  __syncthreads();
  if ((d & 63) == 0) {
#pragma unroll
    for (int t = 0; t < 5; ++t) w5[d >> 6][t] = pv[t];
  }
  __syncthreads();
  if (d < 5) g_s50[m * 5 + d] = w5[0][d] + w5[1][d] + w5[2][d] + w5[3][d];
}

// ---------------- fused cell(fresh rows) + decide + merge ----------------
__global__ __launch_bounds__(256) void k_cellmerge(
    const float* __restrict__ imask, const float* __restrict__ decW,
    const float* __restrict__ decb, const float* __restrict__ b2,
    const float* __restrict__ ln2g, const float* __restrict__ ln2b,
    int i, int last) {
  const int b = blockIdx.x, grp = blockIdx.y;
  const int tid = threadIdx.x, st = tid, lane = tid & 63, wv = tid >> 6;
  const int Sc = 31 - i;
  const int buf = i & 1;
  const int n32 = (b >> 2) * 32;
  __shared__ float sh_nhf[2][256];
  __shared__ float sh_s5f[2][5];
  __shared__ float red4[4];
  __shared__ float w5s[4][5];
  __shared__ int sh_k;
  __shared__ float sh_sv;
  int slot0 = -1, slot1 = -1;
  if (i > 0) { slot0 = g_slots[buf][2 * b]; slot1 = g_slots[buf][2 * b + 1]; }
  const float* s5Src = (i == 0) ? (g_s50 + (b >> 2) * kP0 * 5) : (g_s5[buf] + b * kP0 * 5);
  const float* nhSrcG = (i == 0) ? (g_nh0 + (size_t)(b >> 2) * kP0 * 256)
                                 : (g_nh[buf] + (size_t)b * kP0 * 256);
  const float* stOld = g_state[buf] + b * 8192;
  float* stNew = g_state[(i + 1) & 1] + b * 8192;
  float* nhDst = g_nh[(i + 1) & 1] + (size_t)b * kP0 * 256;
  float* s5Dst = g_s5[(i + 1) & 1] + b * kP0 * 5;
  float done = imask[n32 + i + 1];

  // ---- phase A: fresh-row cell (redundant per WG of b; block-uniform branches) ----
  if (i > 0) {
#pragma unroll 1
    for (int s = 0; s < 2; ++s) {
      int j = (s == 0) ? slot0 : slot1;
      if (j < 0) continue;
      int sr = 2 * b + s;
      float c[4];
#pragma unroll
      for (int q = 0; q < 4; ++q) {
        int g = sr * 1024 + q * 256 + st;
        float v = ((g_p2[0][g] + g_p2[1][g]) + g_p2[2][g]) + g_p2[3][g];
        c[q] = v + b2[q * 256 + st];
      }
      float l = stOld[j * 256 + st];
      float r = stOld[(j + 1) * 256 + st];
      float f1 = 1.0f / (1.0f + expf(-c[0]));
      float f2 = 1.0f / (1.0f + expf(-c[1]));
      float ig = 1.0f / (1.0f + expf(-c[2]));
      float pre = f1 * l + f2 * r + ig * c[3];
      float mean = blockSum256(pre, red4, st) * (1.0f / 256.0f);
      float cen = pre - mean;
      float var = blockSum256(cen * cen, red4, st) * (1.0f / 256.0f);
      float nh = cen / sqrtf(var + 1e-5f) * ln2g[st] + ln2b[st];
      sh_nhf[s][st] = nh;
      float mv = imask[n32 + i + 1 + j];
      float nhm = nh * mv;
      float pv[5];
#pragma unroll
      for (int t = 0; t < 5; ++t) pv[t] = nhm * decW[t * 256 + st];
#pragma unroll
      for (int t = 0; t < 5; ++t) {
        float v = pv[t];
#pragma unroll
        for (int o = 32; o > 0; o >>= 1) v += __shfl_down(v, o, 64);
        pv[t] = v;
      }
      __syncthreads();
      if (lane == 0) {
#pragma unroll
        for (int t = 0; t < 5; ++t) w5s[wv][t] = pv[t];
      }
      __syncthreads();
      if (st < 5) sh_s5f[s][st] = w5s[0][st] + w5s[1][st] + w5s[2][st] + w5s[3][st];
    }
  }
  __syncthreads();

  // ---- phase B: decide (wave 0), bit-exact round-2 math ----
  if (!last && tid < 64) {
    int j = lane;
    bool act = j < Sc;
    float mv = 0.f, lg = 0.f;
    if (act) {
      mv = imask[n32 + i + 1 + j];
      float t5 = decb[0];
      if (j >= 2) {
        int rw = j - 2;
        t5 += (i > 0 && rw == slot0) ? sh_s5f[0][0] : (i > 0 && rw == slot1) ? sh_s5f[1][0] : s5Src[rw * 5 + 0];
      }
      if (j >= 1) {
        int rw = j - 1;
        t5 += (i > 0 && rw == slot0) ? sh_s5f[0][1] : (i > 0 && rw == slot1) ? sh_s5f[1][1] : s5Src[rw * 5 + 1];
      }
      {
        int rw = j;
        t5 += (i > 0 && rw == slot0) ? sh_s5f[0][2] : (i > 0 && rw == slot1) ? sh_s5f[1][2] : s5Src[rw * 5 + 2];
      }
      if (j + 1 < Sc) {
        int rw = j + 1;
        t5 += (i > 0 && rw == slot0) ? sh_s5f[0][3] : (i > 0 && rw == slot1) ? sh_s5f[1][3] : s5Src[rw * 5 + 3];
      }
      if (j + 2 < Sc) {
        int rw = j + 2;
        t5 += (i > 0 && rw == slot0) ? sh_s5f[0][4] : (i > 0 && rw == slot1) ? sh_s5f[1][4] : s5Src[rw * 5 + 4];
      }
      lg = t5 / 35.77708763999664f;
    }
    uint32_t fk0, fk1, o0, o1;
    tf2x32(0u, 1234u, 0u, (uint32_t)i, fk0, fk1);
    uint32_t idx = (uint32_t)(b * Sc + j);
    tf2x32(fk0, fk1, 0u, idx, o0, o1);
    uint32_t bits = o0 ^ o1;
    float u = __uint_as_float((bits >> 9) | 0x3f800000u) - 1.0f;
    float gum = -logf(-logf(u + 1e-20f) + 1e-20f);
    float z = lg + gum;
    float zm = waveMax64(act ? z : -3.0e38f);
    float e = act ? expf(z - zm) : 0.f;
    float p = e / waveSum64(e);
    float y = act ? (p * mv + 1e-20f) : 0.f;
    float ys = y / waveSum64(y);
    float av = act ? ys : -1.f;
    int ai = j;
#pragma unroll
    for (int o = 32; o > 0; o >>= 1) {
      float ov = __shfl_xor(av, o, 64);
      int oi = __shfl_xor(ai, o, 64);
      if (ov > av || (ov == av && oi < ai)) { av = ov; ai = oi; }
    }
    float lm = waveMax64(act ? lg : -3.0e38f);
    float e2 = act ? expf(lg - lm) : 0.f;
    float p2 = e2 / waveSum64(e2);
    float y2 = act ? (p2 * mv + 1e-20f) : 0.f;
    float ps = y2 / waveSum64(y2);
    float ysk = __shfl(ys, ai, 64);
    float psk = __shfl(ps, ai, 64);
    float sv = (1.0f - ysk) + ysk;
    if (j == 0) {
      sh_k = ai;
      sh_sv = sv;
      if (grp == 0) {
        g_accu[b] += done * logf(sv * psk + 1e-20f);
        int s0 = -1, s1 = -1;
        if (done != 0.0f) {
          if (ai >= 1) s0 = ai - 1;
          if (ai <= Sc - 2) s1 = ai;
        }
        g_slots[(i + 1) & 1][2 * b] = s0;
        g_slots[(i + 1) & 1][2 * b + 1] = s1;
      }
    }
  }
  __syncthreads();

  // ---- last step (i==30): no select, state -> single row ----
  if (last) {
    if (grp == 0 && wv == 0) {
      float4 ol = *(const float4*)&stOld[lane * 4];
      float4 nh4;
      if (slot0 == 0) nh4 = *(const float4*)&sh_nhf[0][lane * 4];
      else if (slot1 == 0) nh4 = *(const float4*)&sh_nhf[1][lane * 4];
      else nh4 = *(const float4*)&nhSrcG[lane * 4];
      float4 o4;
      o4.x = done * nh4.x + (1.0f - done) * ol.x;
      o4.y = done * nh4.y + (1.0f - done) * ol.y;
      o4.z = done * nh4.z + (1.0f - done) * ol.z;
      o4.w = done * nh4.w + (1.0f - done) * ol.w;
      *(float4*)&stNew[lane * 4] = o4;
    }
    return;
  }

  // ---- phase C: merge + shift (2 rows per wave) ----
  int k = sh_k;
  float sv = sh_sv;
#pragma unroll 1
  for (int rr = 0; rr < 2; ++rr) {
    int jrow = grp * 8 + wv * 2 + rr;
    if (jrow >= Sc) continue;
    float4 ol = *(const float4*)&stOld[jrow * 256 + lane * 4];
    float4 ov4;
    if (done != 0.0f) {
      float4 mg;
      if (jrow < k) {
        mg = ol;
      } else if (jrow == k) {
        float4 nh4 = (i > 0 && k == slot0) ? *(const float4*)&sh_nhf[0][lane * 4]
                   : (i > 0 && k == slot1) ? *(const float4*)&sh_nhf[1][lane * 4]
                   : *(const float4*)&nhSrcG[k * 256 + lane * 4];
        mg.x = sv * nh4.x + (1.0f - sv) * ol.x;
        mg.y = sv * nh4.y + (1.0f - sv) * ol.y;
        mg.z = sv * nh4.z + (1.0f - sv) * ol.z;
        mg.w = sv * nh4.w + (1.0f - sv) * ol.w;
      } else {
        float4 orr = *(const float4*)&stOld[(jrow + 1) * 256 + lane * 4];
        mg.x = (1.0f - sv) * ol.x + sv * orr.x;
        mg.y = (1.0f - sv) * ol.y + sv * orr.y;
        mg.z = (1.0f - sv) * ol.z + sv * orr.z;
        mg.w = (1.0f - sv) * ol.w + sv * orr.w;
      }
      ov4.x = done * mg.x + (1.0f - done) * ol.x;
      ov4.y = done * mg.y + (1.0f - done) * ol.y;
      ov4.z = done * mg.z + (1.0f - done) * ol.z;
      ov4.w = done * mg.w + (1.0f - done) * ol.w;
    } else {
      ov4 = ol;
    }
    *(float4*)&stNew[jrow * 256 + lane * 4] = ov4;
    if (jrow < Sc - 1) {
      int src = (done != 0.0f && jrow > k) ? jrow + 1 : jrow;
      float4 nv = (i > 0 && src == slot0) ? *(const float4*)&sh_nhf[0][lane * 4]
                : (i > 0 && src == slot1) ? *(const float4*)&sh_nhf[1][lane * 4]
                : *(const float4*)&nhSrcG[src * 256 + lane * 4];
      *(float4*)&nhDst[jrow * 256 + lane * 4] = nv;
      float mv2 = imask[n32 + i + 2 + jrow];
      float pv[5];
#pragma unroll
      for (int t = 0; t < 5; ++t) {
        const float* dw = decW + t * 256 + lane * 4;
        pv[t] = (nv.x * dw[0] + nv.y * dw[1] + nv.z * dw[2] + nv.w * dw[3]) * mv2;
      }
#pragma unroll
      for (int t = 0; t < 5; ++t) {
        float v = pv[t];
#pragma unroll
        for (int o = 32; o > 0; o >>= 1) v += __shfl_down(v, o, 64);
        pv[t] = v;
      }
      if (lane == 0) {
#pragma unroll
        for (int t = 0; t < 5; ++t) s5Dst[jrow * 5 + t] = pv[t];
      }
    }
  }
}

// ---------------- final weighted sum over B ----------------
__global__ __launch_bounds__(256) void k_final(float* __restrict__ out) {
  int n = blockIdx.x, d = threadIdx.x;
  float a0 = g_accu[n * 4 + 0], a1 = g_accu[n * 4 + 1];
  float a2 = g_accu[n * 4 + 2], a3 = g_accu[n * 4 + 3];
  float mx = fmaxf(fmaxf(a0, a1), fmaxf(a2, a3));
  float e0 = expf(a0 - mx), e1 = expf(a1 - mx), e2 = expf(a2 - mx), e3 = expf(a3 - mx);
  float ssum = e0 + e1 + e2 + e3;
  const float* st1 = g_state[1];
  float h0 = st1[(n * 4 + 0) * 8192 + d];
  float h1 = st1[(n * 4 + 1) * 8192 + d];
  float h2 = st1[(n * 4 + 2) * 8192 + d];
  float h3 = st1[(n * 4 + 3) * 8192 + d];
  out[n * 256 + d] = (e0 / ssum) * h0 + (e1 / ssum) * h1 + (e2 / ssum) * h2 + (e3 / ssum) * h3;
}

extern "C" void kernel_launch(void* const* d_in, const int* in_sizes, int n_in,
                              void* d_out, int out_size, void* d_ws, size_t ws_size,
                              hipStream_t stream) {
  (void)in_sizes; (void)n_in; (void)d_ws; (void)ws_size; (void)out_size;
  const float* x = (const float*)d_in[0];
  const float* imask = (const float*)d_in[1];
  const float* wW = (const float*)d_in[2];
  const float* wb = (const float*)d_in[3];
  const float* lng = (const float*)d_in[4];
  const float* lnb = (const float*)d_in[5];
  const float* w1 = (const float*)d_in[6];
  const float* b1 = (const float*)d_in[7];
  const float* w2 = (const float*)d_in[8];
  const float* b2 = (const float*)d_in[9];
  const float* ln2g = (const float*)d_in[10];
  const float* ln2b = (const float*)d_in[11];
  const float* decW = (const float*)d_in[12];
  const float* decb = (const float*)d_in[13];
  float* out = (float*)d_out;

  k_embed<<<dim3(512), dim3(256), 0, stream>>>(x, wW, wb, lng, lnb);
  k_g1s<<<dim3(16, 16), dim3(256), 0, stream>>>(w1, b1);
  k_g2s<<<dim3(16, 16), dim3(256), 0, stream>>>(w2);
  k_cellfull<<<dim3(kM0), dim3(256), 0, stream>>>(imask, ln2g, ln2b, decW, b2);
  k_cellmerge<<<dim3(64, 4), dim3(256), 0, stream>>>(imask, decW, decb, b2, ln2g, ln2b, 0, 0);
  for (int i = 1; i <= 30; ++i) {
    k_g1t<<<dim3(16, 4, 4), dim3(256), 0, stream>>>(w1, i & 1);
    k_g2t<<<dim3(16, 4, 4), dim3(256), 0, stream>>>(w2, b1);
    int lastf = (i == 30) ? 1 : 0;
    k_cellmerge<<<dim3(64, lastf ? 1 : 4), dim3(256), 0, stream>>>(imask, decW, decb, b2,
                                                                   ln2g, ln2b, i, lastf);
  }
  k_final<<<dim3(16), dim3(256), 0, stream>>>(out);
}

// Round 5
// 1244.319 us; speedup vs baseline: 12.7242x; 1.0557x over previous
//
#include <hip/hip_runtime.h>
#include <cstdint>
#include <cstddef>

namespace {
constexpr int kP0 = 31;
constexpr int kM0 = 496;   // 16 n-seqs * 31 pairs at step 0
}

// ---------------- device state ----------------
__device__ float g_state[2][64 * 32 * 256];     // ping-pong per-b state
__device__ float g_nh[2][64 * kP0 * 256];       // pair-row cell outputs (b-indexed)
__device__ float g_s5[2][64 * kP0 * 5];
__device__ float g_nh0[kM0 * 256];              // step-0 n-indexed
__device__ float g_s50[kM0 * 5];
__device__ float g_inter0[(size_t)kM0 * 1024];
__device__ float g_cont0[(size_t)kM0 * 1024];
__device__ float g_p1[4][128 * 1024];           // tail g1 split-K partials
__device__ float g_p2[4][128 * 1024];           // tail g2 split-K partials
__device__ float g_accu[64];
__device__ int g_slots[2][128];                 // parity-buffered fresh-row indices

// ---------------- threefry2x32 (bit-exact jax, verified passing) ----------------
__device__ __forceinline__ void tf2x32(uint32_t k0, uint32_t k1, uint32_t x0,
                                       uint32_t x1, uint32_t& o0, uint32_t& o1) {
  uint32_t ks2 = k0 ^ k1 ^ 0x1BD11BDAu;
  x0 += k0; x1 += k1;
#define TF_ROT(v, r) (((v) << (r)) | ((v) >> (32 - (r))))
#define TF_RD(r) { x0 += x1; x1 = TF_ROT(x1, r); x1 ^= x0; }
  TF_RD(13) TF_RD(15) TF_RD(26) TF_RD(6)   x0 += k1;  x1 += ks2 + 1u;
  TF_RD(17) TF_RD(29) TF_RD(16) TF_RD(24)  x0 += ks2; x1 += k0 + 2u;
  TF_RD(13) TF_RD(15) TF_RD(26) TF_RD(6)   x0 += k0;  x1 += k1 + 3u;
  TF_RD(17) TF_RD(29) TF_RD(16) TF_RD(24)  x0 += k1;  x1 += ks2 + 4u;
  TF_RD(13) TF_RD(15) TF_RD(26) TF_RD(6)   x0 += ks2; x1 += k0 + 5u;
  o0 = x0; o1 = x1;
#undef TF_RD
#undef TF_ROT
}

__device__ __forceinline__ float blockSum256(float v, float* red4, int tid) {
#pragma unroll
  for (int o = 32; o > 0; o >>= 1) v += __shfl_down(v, o, 64);
  __syncthreads();
  if ((tid & 63) == 0) red4[tid >> 6] = v;
  __syncthreads();
  return red4[0] + red4[1] + red4[2] + red4[3];
}
__device__ __forceinline__ float waveMax64(float v) {
#pragma unroll
  for (int o = 32; o > 0; o >>= 1) v = fmaxf(v, __shfl_xor(v, o, 64));
  return v;
}
__device__ __forceinline__ float waveSum64(float v) {
#pragma unroll
  for (int o = 32; o > 0; o >>= 1) v += __shfl_xor(v, o, 64);
  return v;
}
__device__ __forceinline__ float geluf(float v) {
  return 0.5f * v * (1.0f + erff(v * 0.70710678118654752440f));
}

// ---------------- embed + LN, replicate to B copies ----------------
__global__ __launch_bounds__(256) void k_embed(const float* __restrict__ x,
                                               const float* __restrict__ wW,
                                               const float* __restrict__ wb,
                                               const float* __restrict__ lng,
                                               const float* __restrict__ lnb) {
  int row = blockIdx.x;  // n*32 + s
  int d = threadIdx.x;
  __shared__ float xs[256];
  __shared__ float red4[4];
  xs[d] = x[row * 256 + d];
  __syncthreads();
  float acc = wb[d];
  for (int k = 0; k < 256; ++k) acc = fmaf(xs[k], wW[k * 256 + d], acc);
  float mean = blockSum256(acc, red4, d) * (1.0f / 256.0f);
  float cen = acc - mean;
  float var = blockSum256(cen * cen, red4, d) * (1.0f / 256.0f);
  float o = cen / sqrtf(var + 1e-5f) * lng[d] + lnb[d];
  int n = row >> 5, s = row & 31;
#pragma unroll
  for (int bb = 0; bb < 4; ++bb)
    g_state[0][((n * 4 + bb) * 32 + s) * 256 + d] = o;
  if (row == 0 && d < 64) g_accu[d] = 0.0f;
}

// =============== step-0 GEMMs: 32x64 tiles, reg-dbuf K-chunks, XCD-swizzled ===============

// step-0 g1: inter0 = gelu(state_rows @ w1 + b1), K=512 sequential
__global__ __launch_bounds__(256) void k_g1s(const float* __restrict__ w1,
                                             const float* __restrict__ b1) {
  __shared__ float As[64][33];
  __shared__ float Ws[64][68];
  const int tid = threadIdx.x;
  // XCD swizzle: 16 rowB blocks sharing a colB w1-slice land on one XCD
  const int wgid = blockIdx.x;
  const int tsw = wgid >> 3;
  const int colB = ((wgid & 7) + 8 * (tsw & 1)) * 64;
  const int rowB = (tsw >> 1) * 32;
  const int row = tid & 15, cg = tid >> 4;
  const int ar = tid >> 4, ak = (tid & 15) * 4;
  const float *Ab0, *Ab1;
  {
    int m0 = rowB + ar; if (m0 > kM0 - 1) m0 = kM0 - 1;
    int m1 = rowB + ar + 16; if (m1 > kM0 - 1) m1 = kM0 - 1;
    int n0 = m0 / 31, j0 = m0 - n0 * 31;
    int n1 = m1 / 31, j1 = m1 - n1 * 31;
    Ab0 = g_state[0] + (n0 * 4) * 8192 + j0 * 256;
    Ab1 = g_state[0] + (n1 * 4) * 8192 + j1 * 256;
  }
  float4 aR0 = *(const float4*)&Ab0[ak];
  float4 aR1 = *(const float4*)&Ab1[ak];
  float4 wR[4];
#pragma unroll
  for (int q = 0; q < 4; ++q) {
    int f = tid + q * 256; int kk = f >> 4, c4 = f & 15;
    wR[q] = *(const float4*)&w1[(size_t)kk * 1024 + colB + c4 * 4];
  }
  float acc0[4] = {}, acc1[4] = {};
  for (int c = 0; c < 8; ++c) {
    As[ak + 0][ar] = aR0.x; As[ak + 1][ar] = aR0.y; As[ak + 2][ar] = aR0.z; As[ak + 3][ar] = aR0.w;
    As[ak + 0][ar + 16] = aR1.x; As[ak + 1][ar + 16] = aR1.y; As[ak + 2][ar + 16] = aR1.z; As[ak + 3][ar + 16] = aR1.w;
#pragma unroll
    for (int q = 0; q < 4; ++q) {
      int f = tid + q * 256; int kk = f >> 4, c4 = f & 15;
      *(float4*)&Ws[kk][c4 * 4] = wR[q];
    }
    __syncthreads();
    if (c < 7) {
      int kb = (c + 1) * 64;
      aR0 = *(const float4*)&Ab0[kb + ak];
      aR1 = *(const float4*)&Ab1[kb + ak];
#pragma unroll
      for (int q = 0; q < 4; ++q) {
        int f = tid + q * 256; int kk = f >> 4, c4 = f & 15;
        wR[q] = *(const float4*)&w1[(size_t)(kb + kk) * 1024 + colB + c4 * 4];
      }
    }
#pragma unroll
    for (int kk = 0; kk < 64; ++kk) {
      float a0 = As[kk][row], a1 = As[kk][row + 16];
      float4 w = *(const float4*)&Ws[kk][cg * 4];
      acc0[0] = fmaf(a0, w.x, acc0[0]); acc0[1] = fmaf(a0, w.y, acc0[1]);
      acc0[2] = fmaf(a0, w.z, acc0[2]); acc0[3] = fmaf(a0, w.w, acc0[3]);
      acc1[0] = fmaf(a1, w.x, acc1[0]); acc1[1] = fmaf(a1, w.y, acc1[1]);
      acc1[2] = fmaf(a1, w.z, acc1[2]); acc1[3] = fmaf(a1, w.w, acc1[3]);
    }
    __syncthreads();
  }
  int col = colB + cg * 4;
  float4 bb = *(const float4*)&b1[col];
  int m0 = rowB + row, m1 = rowB + row + 16;
  if (m0 < kM0) {
    float4 o;
    o.x = geluf(acc0[0] + bb.x); o.y = geluf(acc0[1] + bb.y);
    o.z = geluf(acc0[2] + bb.z); o.w = geluf(acc0[3] + bb.w);
    *(float4*)&g_inter0[(size_t)m0 * 1024 + col] = o;
  }
  if (m1 < kM0) {
    float4 o;
    o.x = geluf(acc1[0] + bb.x); o.y = geluf(acc1[1] + bb.y);
    o.z = geluf(acc1[2] + bb.z); o.w = geluf(acc1[3] + bb.w);
    *(float4*)&g_inter0[(size_t)m1 * 1024 + col] = o;
  }
}

// step-0 g2: cont0 = inter0 @ w2 (raw; b2 added in cellfull), K=1024 sequential
__global__ __launch_bounds__(256) void k_g2s(const float* __restrict__ w2) {
  __shared__ float As[64][33];
  __shared__ float Ws[64][68];
  const int tid = threadIdx.x;
  const int wgid = blockIdx.x;
  const int tsw = wgid >> 3;
  const int colB = ((wgid & 7) + 8 * (tsw & 1)) * 64;
  const int rowB = (tsw >> 1) * 32;
  const int row = tid & 15, cg = tid >> 4;
  const int ar = tid >> 4, ak = (tid & 15) * 4;
  int m0s = rowB + ar; if (m0s > kM0 - 1) m0s = kM0 - 1;
  int m1s = rowB + ar + 16; if (m1s > kM0 - 1) m1s = kM0 - 1;
  const float* Ab0 = g_inter0 + (size_t)m0s * 1024;
  const float* Ab1 = g_inter0 + (size_t)m1s * 1024;
  float4 aR0 = *(const float4*)&Ab0[ak];
  float4 aR1 = *(const float4*)&Ab1[ak];
  float4 wR[4];
#pragma unroll
  for (int q = 0; q < 4; ++q) {
    int f = tid + q * 256; int kk = f >> 4, c4 = f & 15;
    wR[q] = *(const float4*)&w2[(size_t)kk * 1024 + colB + c4 * 4];
  }
  float acc0[4] = {}, acc1[4] = {};
  for (int c = 0; c < 16; ++c) {
    As[ak + 0][ar] = aR0.x; As[ak + 1][ar] = aR0.y; As[ak + 2][ar] = aR0.z; As[ak + 3][ar] = aR0.w;
    As[ak + 0][ar + 16] = aR1.x; As[ak + 1][ar + 16] = aR1.y; As[ak + 2][ar + 16] = aR1.z; As[ak + 3][ar + 16] = aR1.w;
#pragma unroll
    for (int q = 0; q < 4; ++q) {
      int f = tid + q * 256; int kk = f >> 4, c4 = f & 15;
      *(float4*)&Ws[kk][c4 * 4] = wR[q];
    }
    __syncthreads();
    if (c < 15) {
      int kb = (c + 1) * 64;
      aR0 = *(const float4*)&Ab0[kb + ak];
      aR1 = *(const float4*)&Ab1[kb + ak];
#pragma unroll
      for (int q = 0; q < 4; ++q) {
        int f = tid + q * 256; int kk = f >> 4, c4 = f & 15;
        wR[q] = *(const float4*)&w2[(size_t)(kb + kk) * 1024 + colB + c4 * 4];
      }
    }
#pragma unroll
    for (int kk = 0; kk < 64; ++kk) {
      float a0 = As[kk][row], a1 = As[kk][row + 16];
      float4 w = *(const float4*)&Ws[kk][cg * 4];
      acc0[0] = fmaf(a0, w.x, acc0[0]); acc0[1] = fmaf(a0, w.y, acc0[1]);
      acc0[2] = fmaf(a0, w.z, acc0[2]); acc0[3] = fmaf(a0, w.w, acc0[3]);
      acc1[0] = fmaf(a1, w.x, acc1[0]); acc1[1] = fmaf(a1, w.y, acc1[1]);
      acc1[2] = fmaf(a1, w.z, acc1[2]); acc1[3] = fmaf(a1, w.w, acc1[3]);
    }
    __syncthreads();
  }
  int col = colB + cg * 4;
  int m0 = rowB + row, m1 = rowB + row + 16;
  if (m0 < kM0) {
    float4 o = {acc0[0], acc0[1], acc0[2], acc0[3]};
    *(float4*)&g_cont0[(size_t)m0 * 1024 + col] = o;
  }
  if (m1 < kM0) {
    float4 o = {acc1[0], acc1[1], acc1[2], acc1[3]};
    *(float4*)&g_cont0[(size_t)m1 * 1024 + col] = o;
  }
}

// tail g2: partials over K-range [Ks*256, +256); A assembled as gelu(sum(p1)+b1)
__device__ __forceinline__ float4 g2t_loadA(int grow, int kpos, const float* __restrict__ b1) {
  size_t g = (size_t)grow * 1024 + kpos;
  float4 p0 = *(const float4*)&g_p1[0][g];
  float4 p1 = *(const float4*)&g_p1[1][g];
  float4 p2 = *(const float4*)&g_p1[2][g];
  float4 p3 = *(const float4*)&g_p1[3][g];
  float4 bb = *(const float4*)&b1[kpos];
  float4 r;
  r.x = geluf(p0.x + p1.x + p2.x + p3.x + bb.x);
  r.y = geluf(p0.y + p1.y + p2.y + p3.y + bb.y);
  r.z = geluf(p0.z + p1.z + p2.z + p3.z + bb.z);
  r.w = geluf(p0.w + p1.w + p2.w + p3.w + bb.w);
  return r;
}

__global__ __launch_bounds__(256) void k_g2t(const float* __restrict__ w2,
                                             const float* __restrict__ b1) {
  __shared__ float As[64][33];
  __shared__ float Ws[64][68];
  const int tid = threadIdx.x;
  const int colB = blockIdx.x * 64;
  const int rowB = blockIdx.y * 32;
  const int Ks = blockIdx.z;
  const int kb0 = Ks * 256;
  const int row = tid & 15, cg = tid >> 4;
  const int ar = tid >> 4, ak = (tid & 15) * 4;
  const int grow0 = rowB + ar, grow1 = rowB + ar + 16;
  float4 aR0 = g2t_loadA(grow0, kb0 + ak, b1);
  float4 aR1 = g2t_loadA(grow1, kb0 + ak, b1);
  float4 wR[4];
#pragma unroll
  for (int q = 0; q < 4; ++q) {
    int f = tid + q * 256; int kk = f >> 4, c4 = f & 15;
    wR[q] = *(const float4*)&w2[(size_t)(kb0 + kk) * 1024 + colB + c4 * 4];
  }
  float acc0[4] = {}, acc1[4] = {};
  for (int c = 0; c < 4; ++c) {
    As[ak + 0][ar] = aR0.x; As[ak + 1][ar] = aR0.y; As[ak + 2][ar] = aR0.z; As[ak + 3][ar] = aR0.w;
    As[ak + 0][ar + 16] = aR1.x; As[ak + 1][ar + 16] = aR1.y; As[ak + 2][ar + 16] = aR1.z; As[ak + 3][ar + 16] = aR1.w;
#pragma unroll
    for (int q = 0; q < 4; ++q) {
      int f = tid + q * 256; int kk = f >> 4, c4 = f & 15;
      *(float4*)&Ws[kk][c4 * 4] = wR[q];
    }
    __syncthreads();
    if (c < 3) {
      int kb = kb0 + (c + 1) * 64;
      aR0 = g2t_loadA(grow0, kb + ak, b1);
      aR1 = g2t_loadA(grow1, kb + ak, b1);
#pragma unroll
      for (int q = 0; q < 4; ++q) {
        int f = tid + q * 256; int kk = f >> 4, c4 = f & 15;
        wR[q] = *(const float4*)&w2[(size_t)(kb + kk) * 1024 + colB + c4 * 4];
      }
    }
#pragma unroll
    for (int kk = 0; kk < 64; ++kk) {
      float a0 = As[kk][row], a1 = As[kk][row + 16];
      float4 w = *(const float4*)&Ws[kk][cg * 4];
      acc0[0] = fmaf(a0, w.x, acc0[0]); acc0[1] = fmaf(a0, w.y, acc0[1]);
      acc0[2] = fmaf(a0, w.z, acc0[2]); acc0[3] = fmaf(a0, w.w, acc0[3]);
      acc1[0] = fmaf(a1, w.x, acc1[0]); acc1[1] = fmaf(a1, w.y, acc1[1]);
      acc1[2] = fmaf(a1, w.z, acc1[2]); acc1[3] = fmaf(a1, w.w, acc1[3]);
    }
    __syncthreads();
  }
  int col = colB + cg * 4;
  {
    float4 o = {acc0[0], acc0[1], acc0[2], acc0[3]};
    *(float4*)&g_p2[Ks][(rowB + row) * 1024 + col] = o;
  }
  {
    float4 o = {acc1[0], acc1[1], acc1[2], acc1[3]};
    *(float4*)&g_p2[Ks][(rowB + row + 16) * 1024 + col] = o;
  }
}

// ---------------- step-0 cell (all 496 rows) ----------------
__global__ __launch_bounds__(256) void k_cellfull(const float* __restrict__ imask,
                                                  const float* __restrict__ ln2g,
                                                  const float* __restrict__ ln2b,
                                                  const float* __restrict__ decW,
                                                  const float* __restrict__ b2) {
  int m = blockIdx.x;    // n*31 + j
  int d = threadIdx.x;
  int n = m / 31, j = m - n * 31;
  const float* st = g_state[0] + (n * 4) * 8192;
  const float* crow = g_cont0 + (size_t)m * 1024;
  float c0 = crow[d] + b2[d];
  float c1 = crow[256 + d] + b2[256 + d];
  float c2 = crow[512 + d] + b2[512 + d];
  float c3 = crow[768 + d] + b2[768 + d];
  float l = st[j * 256 + d];
  float r = st[(j + 1) * 256 + d];
  float f1 = 1.0f / (1.0f + expf(-c0));
  float f2 = 1.0f / (1.0f + expf(-c1));
  float ig = 1.0f / (1.0f + expf(-c2));
  float pre = f1 * l + f2 * r + ig * c3;
  __shared__ float red4[4];
  __shared__ float w5[4][5];
  float mean = blockSum256(pre, red4, d) * (1.0f / 256.0f);
  float cen = pre - mean;
  float var = blockSum256(cen * cen, red4, d) * (1.0f / 256.0f);
  float nh = cen / sqrtf(var + 1e-5f) * ln2g[d] + ln2b[d];
  g_nh0[m * 256 + d] = nh;
  float mv = imask[n * 32 + 1 + j];
  float nhm = nh * mv;
  float pv[5];
#pragma unroll
  for (int t = 0; t < 5; ++t) pv[t] = nhm * decW[t * 256 + d];
#pragma unroll
  for (int t = 0; t < 5; ++t)
#pragma unroll
    for (int o = 32; o > 0; o >>= 1) pv[t] += __shfl_down(pv[t], o, 64);
  __syncthreads();
  if ((d & 63) == 0) {
#pragma unroll
    for (int t = 0; t < 5; ++t) w5[d >> 6][t] = pv[t];
  }
  __syncthreads();
  if (d < 5) g_s50[m * 5 + d] = w5[0][d] + w5[1][d] + w5[2][d] + w5[3][d];
}

// ---------------- fused cell(fresh) + decide + merge + next-step g1 partials ----------------
__global__ __launch_bounds__(256) void k_cm(
    const float* __restrict__ imask, const float* __restrict__ decW,
    const float* __restrict__ decb, const float* __restrict__ b2,
    const float* __restrict__ ln2g, const float* __restrict__ ln2b,
    const float* __restrict__ w1, int i, int last) {
  const int b = blockIdx.x, grp = blockIdx.y;
  const int tid = threadIdx.x, st = tid, lane = tid & 63, wv = tid >> 6;
  const int Sc = 31 - i;
  const int buf = i & 1;
  const int n32 = (b >> 2) * 32;
  __shared__ float sh_nhf[2][256];
  __shared__ float sh_s5f[2][5];
  __shared__ float sA[3][256];
  __shared__ float red4[4];
  __shared__ float w5s[4][5];
  __shared__ int sh_k;
  __shared__ float sh_sv;
  int slot0 = -1, slot1 = -1;
  if (i > 0) { slot0 = g_slots[buf][2 * b]; slot1 = g_slots[buf][2 * b + 1]; }
  const float* s5Src = (i == 0) ? (g_s50 + (b >> 2) * kP0 * 5) : (g_s5[buf] + b * kP0 * 5);
  const float* nhSrcG = (i == 0) ? (g_nh0 + (size_t)(b >> 2) * kP0 * 256)
                                 : (g_nh[buf] + (size_t)b * kP0 * 256);
  const float* stOld = g_state[buf] + b * 8192;
  float* stNew = g_state[(i + 1) & 1] + b * 8192;
  float* nhDst = g_nh[(i + 1) & 1] + (size_t)b * kP0 * 256;
  float* s5Dst = g_s5[(i + 1) & 1] + b * kP0 * 5;
  float done = imask[n32 + i + 1];

  // ---- phase A: fresh-row cell (redundant per WG of b; block-uniform branches) ----
  if (i > 0) {
#pragma unroll 1
    for (int s = 0; s < 2; ++s) {
      int j = (s == 0) ? slot0 : slot1;
      if (j < 0) continue;
      int sr = 2 * b + s;
      float c[4];
#pragma unroll
      for (int q = 0; q < 4; ++q) {
        int g = sr * 1024 + q * 256 + st;
        float v = ((g_p2[0][g] + g_p2[1][g]) + g_p2[2][g]) + g_p2[3][g];
        c[q] = v + b2[q * 256 + st];
      }
      float l = stOld[j * 256 + st];
      float r = stOld[(j + 1) * 256 + st];
      float f1 = 1.0f / (1.0f + expf(-c[0]));
      float f2 = 1.0f / (1.0f + expf(-c[1]));
      float ig = 1.0f / (1.0f + expf(-c[2]));
      float pre = f1 * l + f2 * r + ig * c[3];
      float mean = blockSum256(pre, red4, st) * (1.0f / 256.0f);
      float cen = pre - mean;
      float var = blockSum256(cen * cen, red4, st) * (1.0f / 256.0f);
      float nh = cen / sqrtf(var + 1e-5f) * ln2g[st] + ln2b[st];
      sh_nhf[s][st] = nh;
      float mv = imask[n32 + i + 1 + j];
      float nhm = nh * mv;
      float pv[5];
#pragma unroll
      for (int t = 0; t < 5; ++t) pv[t] = nhm * decW[t * 256 + st];
#pragma unroll
      for (int t = 0; t < 5; ++t) {
        float v = pv[t];
#pragma unroll
        for (int o = 32; o > 0; o >>= 1) v += __shfl_down(v, o, 64);
        pv[t] = v;
      }
      __syncthreads();
      if (lane == 0) {
#pragma unroll
        for (int t = 0; t < 5; ++t) w5s[wv][t] = pv[t];
      }
      __syncthreads();
      if (st < 5) sh_s5f[s][st] = w5s[0][st] + w5s[1][st] + w5s[2][st] + w5s[3][st];
    }
  }
  __syncthreads();

  // ---- phase B: decide (wave 0), bit-exact round-2 math ----
  if (!last && tid < 64) {
    int j = lane;
    bool act = j < Sc;
    float mv = 0.f, lg = 0.f;
    if (act) {
      mv = imask[n32 + i + 1 + j];
      float t5 = decb[0];
      if (j >= 2) {
        int rw = j - 2;
        t5 += (i > 0 && rw == slot0) ? sh_s5f[0][0] : (i > 0 && rw == slot1) ? sh_s5f[1][0] : s5Src[rw * 5 + 0];
      }
      if (j >= 1) {
        int rw = j - 1;
        t5 += (i > 0 && rw == slot0) ? sh_s5f[0][1] : (i > 0 && rw == slot1) ? sh_s5f[1][1] : s5Src[rw * 5 + 1];
      }
      {
        int rw = j;
        t5 += (i > 0 && rw == slot0) ? sh_s5f[0][2] : (i > 0 && rw == slot1) ? sh_s5f[1][2] : s5Src[rw * 5 + 2];
      }
      if (j + 1 < Sc) {
        int rw = j + 1;
        t5 += (i > 0 && rw == slot0) ? sh_s5f[0][3] : (i > 0 && rw == slot1) ? sh_s5f[1][3] : s5Src[rw * 5 + 3];
      }
      if (j + 2 < Sc) {
        int rw = j + 2;
        t5 += (i > 0 && rw == slot0) ? sh_s5f[0][4] : (i > 0 && rw == slot1) ? sh_s5f[1][4] : s5Src[rw * 5 + 4];
      }
      lg = t5 / 35.77708763999664f;
    }
    uint32_t fk0, fk1, o0, o1;
    tf2x32(0u, 1234u, 0u, (uint32_t)i, fk0, fk1);
    uint32_t idx = (uint32_t)(b * Sc + j);
    tf2x32(fk0, fk1, 0u, idx, o0, o1);
    uint32_t bits = o0 ^ o1;
    float u = __uint_as_float((bits >> 9) | 0x3f800000u) - 1.0f;
    float gum = -logf(-logf(u + 1e-20f) + 1e-20f);
    float z = lg + gum;
    float zm = waveMax64(act ? z : -3.0e38f);
    float e = act ? expf(z - zm) : 0.f;
    float p = e / waveSum64(e);
    float y = act ? (p * mv + 1e-20f) : 0.f;
    float ys = y / waveSum64(y);
    float av = act ? ys : -1.f;
    int ai = j;
#pragma unroll
    for (int o = 32; o > 0; o >>= 1) {
      float ov = __shfl_xor(av, o, 64);
      int oi = __shfl_xor(ai, o, 64);
      if (ov > av || (ov == av && oi < ai)) { av = ov; ai = oi; }
    }
    float lm = waveMax64(act ? lg : -3.0e38f);
    float e2 = act ? expf(lg - lm) : 0.f;
    float p2 = e2 / waveSum64(e2);
    float y2 = act ? (p2 * mv + 1e-20f) : 0.f;
    float ps = y2 / waveSum64(y2);
    float ysk = __shfl(ys, ai, 64);
    float psk = __shfl(ps, ai, 64);
    float sv = (1.0f - ysk) + ysk;
    if (j == 0) {
      sh_k = ai;
      sh_sv = sv;
      if (grp == 0) {
        g_accu[b] += done * logf(sv * psk + 1e-20f);
        int s0 = -1, s1 = -1;
        if (done != 0.0f) {
          if (ai >= 1) s0 = ai - 1;
          if (ai <= Sc - 2) s1 = ai;
        }
        g_slots[(i + 1) & 1][2 * b] = s0;
        g_slots[(i + 1) & 1][2 * b + 1] = s1;
      }
    }
  }
  __syncthreads();

  // ---- last step (i==30): no select, state -> single row ----
  if (last) {
    if (grp == 0 && wv == 0) {
      float4 ol = *(const float4*)&stOld[lane * 4];
      float4 nh4;
      if (slot0 == 0) nh4 = *(const float4*)&sh_nhf[0][lane * 4];
      else if (slot1 == 0) nh4 = *(const float4*)&sh_nhf[1][lane * 4];
      else nh4 = *(const float4*)&nhSrcG[lane * 4];
      float4 o4;
      o4.x = done * nh4.x + (1.0f - done) * ol.x;
      o4.y = done * nh4.y + (1.0f - done) * ol.y;
      o4.z = done * nh4.z + (1.0f - done) * ol.z;
      o4.w = done * nh4.w + (1.0f - done) * ol.w;
      *(float4*)&stNew[lane * 4] = o4;
    }
    return;
  }

  // ---- phase C: merge + shift (2 rows per wave) ----
  int k = sh_k;
  float sv = sh_sv;
#pragma unroll 1
  for (int rr = 0; rr < 2; ++rr) {
    int jrow = grp * 8 + wv * 2 + rr;
    if (jrow >= Sc) continue;
    float4 ol = *(const float4*)&stOld[jrow * 256 + lane * 4];
    float4 ov4;
    if (done != 0.0f) {
      float4 mg;
      if (jrow < k) {
        mg = ol;
      } else if (jrow == k) {
        float4 nh4 = (i > 0 && k == slot0) ? *(const float4*)&sh_nhf[0][lane * 4]
                   : (i > 0 && k == slot1) ? *(const float4*)&sh_nhf[1][lane * 4]
                   : *(const float4*)&nhSrcG[k * 256 + lane * 4];
        mg.x = sv * nh4.x + (1.0f - sv) * ol.x;
        mg.y = sv * nh4.y + (1.0f - sv) * ol.y;
        mg.z = sv * nh4.z + (1.0f - sv) * ol.z;
        mg.w = sv * nh4.w + (1.0f - sv) * ol.w;
      } else {
        float4 orr = *(const float4*)&stOld[(jrow + 1) * 256 + lane * 4];
        mg.x = (1.0f - sv) * ol.x + sv * orr.x;
        mg.y = (1.0f - sv) * ol.y + sv * orr.y;
        mg.z = (1.0f - sv) * ol.z + sv * orr.z;
        mg.w = (1.0f - sv) * ol.w + sv * orr.w;
      }
      ov4.x = done * mg.x + (1.0f - done) * ol.x;
      ov4.y = done * mg.y + (1.0f - done) * ol.y;
      ov4.z = done * mg.z + (1.0f - done) * ol.z;
      ov4.w = done * mg.w + (1.0f - done) * ol.w;
    } else {
      ov4 = ol;
    }
    *(float4*)&stNew[jrow * 256 + lane * 4] = ov4;
    if (jrow < Sc - 1) {
      int src = (done != 0.0f && jrow > k) ? jrow + 1 : jrow;
      float4 nv = (i > 0 && src == slot0) ? *(const float4*)&sh_nhf[0][lane * 4]
                : (i > 0 && src == slot1) ? *(const float4*)&sh_nhf[1][lane * 4]
                : *(const float4*)&nhSrcG[src * 256 + lane * 4];
      *(float4*)&nhDst[jrow * 256 + lane * 4] = nv;
      float mv2 = imask[n32 + i + 2 + jrow];
      float pv[5];
#pragma unroll
      for (int t = 0; t < 5; ++t) {
        const float* dw = decW + t * 256 + lane * 4;
        pv[t] = (nv.x * dw[0] + nv.y * dw[1] + nv.z * dw[2] + nv.w * dw[3]) * mv2;
      }
#pragma unroll
      for (int t = 0; t < 5; ++t) {
        float v = pv[t];
#pragma unroll
        for (int o = 32; o > 0; o >>= 1) v += __shfl_down(v, o, 64);
        pv[t] = v;
      }
      if (lane == 0) {
#pragma unroll
        for (int t = 0; t < 5; ++t) s5Dst[jrow * 5 + t] = pv[t];
      }
    }
  }

  // ---- phase D: next-step g1 split-K partial (grp = Ks), order-identical to old k_g1t ----
  if (done != 0.0f) {
    __syncthreads();
    {
      int d = st;
      float nhKv = (i > 0 && k == slot0) ? sh_nhf[0][d]
                 : (i > 0 && k == slot1) ? sh_nhf[1][d]
                 : nhSrcG[k * 256 + d];
#pragma unroll
      for (int t = 0; t < 3; ++t) {
        int r = k - 1 + t;
        if (r < 0 || r > Sc - 1) continue;
        float ol = stOld[r * 256 + d];
        float mg;
        if (r < k) mg = ol;
        else if (r == k) mg = sv * nhKv + (1.0f - sv) * ol;
        else mg = (1.0f - sv) * ol + sv * stOld[(r + 1) * 256 + d];
        sA[t][d] = done * mg + (1.0f - done) * ol;
      }
    }
    __syncthreads();
    const int has0 = (k >= 1);
    const int has1 = (k <= Sc - 2);
    const int kb0 = grp * 128;
    const float* A0 = (grp < 2) ? sA[0] : sA[1];   // srow 2b   (jn = k-1): rows k-1,k
    const float* A1 = (grp < 2) ? sA[1] : sA[2];   // srow 2b+1 (jn = k):   rows k,k+1
    const int koff = (grp < 2) ? kb0 : (kb0 - 256);
    const int col = st * 4;
    float a00 = 0.f, a01 = 0.f, a02 = 0.f, a03 = 0.f;
    float a10 = 0.f, a11 = 0.f, a12 = 0.f, a13 = 0.f;
    for (int kk = 0; kk < 128; ++kk) {
      float4 w = *(const float4*)&w1[(size_t)(kb0 + kk) * 1024 + col];
      float av0 = A0[koff + kk];
      float av1 = A1[koff + kk];
      a00 = fmaf(av0, w.x, a00); a01 = fmaf(av0, w.y, a01);
      a02 = fmaf(av0, w.z, a02); a03 = fmaf(av0, w.w, a03);
      a10 = fmaf(av1, w.x, a10); a11 = fmaf(av1, w.y, a11);
      a12 = fmaf(av1, w.z, a12); a13 = fmaf(av1, w.w, a13);
    }
    if (has0) {
      float4 o = {a00, a01, a02, a03};
      *(float4*)&g_p1[grp][(2 * b + 0) * 1024 + col] = o;
    }
    if (has1) {
      float4 o = {a10, a11, a12, a13};
      *(float4*)&g_p1[grp][(2 * b + 1) * 1024 + col] = o;
    }
  }
}

// ---------------- final weighted sum over B ----------------
__global__ __launch_bounds__(256) void k_final(float* __restrict__ out) {
  int n = blockIdx.x, d = threadIdx.x;
  float a0 = g_accu[n * 4 + 0], a1 = g_accu[n * 4 + 1];
  float a2 = g_accu[n * 4 + 2], a3 = g_accu[n * 4 + 3];
  float mx = fmaxf(fmaxf(a0, a1), fmaxf(a2, a3));
  float e0 = expf(a0 - mx), e1 = expf(a1 - mx), e2 = expf(a2 - mx), e3 = expf(a3 - mx);
  float ssum = e0 + e1 + e2 + e3;
  const float* st1 = g_state[1];
  float h0 = st1[(n * 4 + 0) * 8192 + d];
  float h1 = st1[(n * 4 + 1) * 8192 + d];
  float h2 = st1[(n * 4 + 2) * 8192 + d];
  float h3 = st1[(n * 4 + 3) * 8192 + d];
  out[n * 256 + d] = (e0 / ssum) * h0 + (e1 / ssum) * h1 + (e2 / ssum) * h2 + (e3 / ssum) * h3;
}

extern "C" void kernel_launch(void* const* d_in, const int* in_sizes, int n_in,
                              void* d_out, int out_size, void* d_ws, size_t ws_size,
                              hipStream_t stream) {
  (void)in_sizes; (void)n_in; (void)d_ws; (void)ws_size; (void)out_size;
  const float* x = (const float*)d_in[0];
  const float* imask = (const float*)d_in[1];
  const float* wW = (const float*)d_in[2];
  const float* wb = (const float*)d_in[3];
  const float* lng = (const float*)d_in[4];
  const float* lnb = (const float*)d_in[5];
  const float* w1 = (const float*)d_in[6];
  const float* b1 = (const float*)d_in[7];
  const float* w2 = (const float*)d_in[8];
  const float* b2 = (const float*)d_in[9];
  const float* ln2g = (const float*)d_in[10];
  const float* ln2b = (const float*)d_in[11];
  const float* decW = (const float*)d_in[12];
  const float* decb = (const float*)d_in[13];
  float* out = (float*)d_out;

  k_embed<<<dim3(512), dim3(256), 0, stream>>>(x, wW, wb, lng, lnb);
  k_g1s<<<dim3(256), dim3(256), 0, stream>>>(w1, b1);
  k_g2s<<<dim3(256), dim3(256), 0, stream>>>(w2);
  k_cellfull<<<dim3(kM0), dim3(256), 0, stream>>>(imask, ln2g, ln2b, decW, b2);
  k_cm<<<dim3(64, 4), dim3(256), 0, stream>>>(imask, decW, decb, b2, ln2g, ln2b, w1, 0, 0);
  for (int i = 1; i <= 30; ++i) {
    k_g2t<<<dim3(16, 4, 4), dim3(256), 0, stream>>>(w2, b1);
    int lastf = (i == 30) ? 1 : 0;
    k_cm<<<dim3(64, lastf ? 1 : 4), dim3(256), 0, stream>>>(imask, decW, decb, b2,
                                                            ln2g, ln2b, w1, i, lastf);
  }
  k_final<<<dim3(16), dim3(256), 0, stream>>>(out);
}

// Round 6
// 1221.378 us; speedup vs baseline: 12.9632x; 1.0188x over previous
//
#include <hip/hip_runtime.h>
#include <cstdint>
#include <cstddef>

namespace {
constexpr int kP0 = 31;
constexpr int kM0 = 496;   // 16 n-seqs * 31 pairs at step 0
}

// ---------------- device state ----------------
__device__ float g_state[2][64 * 32 * 256];     // ping-pong per-b state
__device__ float g_nh[2][64 * kP0 * 256];       // pair-row cell outputs (b-indexed)
__device__ float g_s5[2][64 * kP0 * 5];
__device__ float g_nh0[kM0 * 256];              // step-0 n-indexed
__device__ float g_s50[kM0 * 5];
__device__ float g_inter0[(size_t)kM0 * 1024];
__device__ float g_cont0[(size_t)kM0 * 1024];
__device__ float g_p1[4][128 * 1024];           // tail g1 split-K partials
__device__ float g_p2[4][128 * 1024];           // tail g2 split-K partials
__device__ float g_accu[64];
__device__ int g_slots[2][128];                 // parity-buffered fresh-row indices

// ---------------- threefry2x32 (bit-exact jax, verified passing) ----------------
__device__ __forceinline__ void tf2x32(uint32_t k0, uint32_t k1, uint32_t x0,
                                       uint32_t x1, uint32_t& o0, uint32_t& o1) {
  uint32_t ks2 = k0 ^ k1 ^ 0x1BD11BDAu;
  x0 += k0; x1 += k1;
#define TF_ROT(v, r) (((v) << (r)) | ((v) >> (32 - (r))))
#define TF_RD(r) { x0 += x1; x1 = TF_ROT(x1, r); x1 ^= x0; }
  TF_RD(13) TF_RD(15) TF_RD(26) TF_RD(6)   x0 += k1;  x1 += ks2 + 1u;
  TF_RD(17) TF_RD(29) TF_RD(16) TF_RD(24)  x0 += ks2; x1 += k0 + 2u;
  TF_RD(13) TF_RD(15) TF_RD(26) TF_RD(6)   x0 += k0;  x1 += k1 + 3u;
  TF_RD(17) TF_RD(29) TF_RD(16) TF_RD(24)  x0 += k1;  x1 += ks2 + 4u;
  TF_RD(13) TF_RD(15) TF_RD(26) TF_RD(6)   x0 += ks2; x1 += k0 + 5u;
  o0 = x0; o1 = x1;
#undef TF_RD
#undef TF_ROT
}

__device__ __forceinline__ float blockSum256(float v, float* red4, int tid) {
#pragma unroll
  for (int o = 32; o > 0; o >>= 1) v += __shfl_down(v, o, 64);
  __syncthreads();
  if ((tid & 63) == 0) red4[tid >> 6] = v;
  __syncthreads();
  return red4[0] + red4[1] + red4[2] + red4[3];
}
__device__ __forceinline__ float waveMax64(float v) {
#pragma unroll
  for (int o = 32; o > 0; o >>= 1) v = fmaxf(v, __shfl_xor(v, o, 64));
  return v;
}
__device__ __forceinline__ float waveSum64(float v) {
#pragma unroll
  for (int o = 32; o > 0; o >>= 1) v += __shfl_xor(v, o, 64);
  return v;
}
__device__ __forceinline__ float geluf(float v) {
  return 0.5f * v * (1.0f + erff(v * 0.70710678118654752440f));
}

// ---------------- embed + LN, replicate to B copies ----------------
__global__ __launch_bounds__(256) void k_embed(const float* __restrict__ x,
                                               const float* __restrict__ wW,
                                               const float* __restrict__ wb,
                                               const float* __restrict__ lng,
                                               const float* __restrict__ lnb) {
  int row = blockIdx.x;  // n*32 + s
  int d = threadIdx.x;
  __shared__ float xs[256];
  __shared__ float red4[4];
  xs[d] = x[row * 256 + d];
  __syncthreads();
  float acc = wb[d];
  for (int k = 0; k < 256; ++k) acc = fmaf(xs[k], wW[k * 256 + d], acc);
  float mean = blockSum256(acc, red4, d) * (1.0f / 256.0f);
  float cen = acc - mean;
  float var = blockSum256(cen * cen, red4, d) * (1.0f / 256.0f);
  float o = cen / sqrtf(var + 1e-5f) * lng[d] + lnb[d];
  int n = row >> 5, s = row & 31;
#pragma unroll
  for (int bb = 0; bb < 4; ++bb)
    g_state[0][((n * 4 + bb) * 32 + s) * 256 + d] = o;
  if (row == 0 && d < 64) g_accu[d] = 0.0f;
}

// =============== step-0 GEMMs: 32x64 tiles, 512 threads (1 row x 4 cols/thread) ===============

// step-0 g1: inter0 = gelu(state_rows @ w1 + b1), K=512 sequential
__global__ __launch_bounds__(512) void k_g1s(const float* __restrict__ w1,
                                             const float* __restrict__ b1) {
  __shared__ float As[64][33];
  __shared__ float Ws[64][68];
  const int tid = threadIdx.x;
  const int wgid = blockIdx.x;
  const int tsw = wgid >> 3;
  const int colB = ((wgid & 7) + 8 * (tsw & 1)) * 64;
  const int rowB = (tsw >> 1) * 32;
  const int row = tid & 31, cg = tid >> 5;
  const int ar = tid >> 4, ak = (tid & 15) * 4;
  const float* Ab;
  {
    int m = rowB + ar; if (m > kM0 - 1) m = kM0 - 1;
    int n = m / 31, j = m - n * 31;
    Ab = g_state[0] + (n * 4) * 8192 + j * 256;
  }
  float4 aR = *(const float4*)&Ab[ak];
  float4 wR[2];
#pragma unroll
  for (int q = 0; q < 2; ++q) {
    int f = tid + q * 512; int kk = f >> 4, c4 = f & 15;
    wR[q] = *(const float4*)&w1[(size_t)kk * 1024 + colB + c4 * 4];
  }
  float acc[4] = {};
  for (int c = 0; c < 8; ++c) {
    As[ak + 0][ar] = aR.x; As[ak + 1][ar] = aR.y;
    As[ak + 2][ar] = aR.z; As[ak + 3][ar] = aR.w;
#pragma unroll
    for (int q = 0; q < 2; ++q) {
      int f = tid + q * 512; int kk = f >> 4, c4 = f & 15;
      *(float4*)&Ws[kk][c4 * 4] = wR[q];
    }
    __syncthreads();
    if (c < 7) {
      int kb = (c + 1) * 64;
      aR = *(const float4*)&Ab[kb + ak];
#pragma unroll
      for (int q = 0; q < 2; ++q) {
        int f = tid + q * 512; int kk = f >> 4, c4 = f & 15;
        wR[q] = *(const float4*)&w1[(size_t)(kb + kk) * 1024 + colB + c4 * 4];
      }
    }
#pragma unroll
    for (int kk = 0; kk < 64; ++kk) {
      float a = As[kk][row];
      float4 w = *(const float4*)&Ws[kk][cg * 4];
      acc[0] = fmaf(a, w.x, acc[0]); acc[1] = fmaf(a, w.y, acc[1]);
      acc[2] = fmaf(a, w.z, acc[2]); acc[3] = fmaf(a, w.w, acc[3]);
    }
    __syncthreads();
  }
  int m = rowB + row;
  int col = colB + cg * 4;
  if (m < kM0) {
    float4 bb = *(const float4*)&b1[col];
    float4 o;
    o.x = geluf(acc[0] + bb.x); o.y = geluf(acc[1] + bb.y);
    o.z = geluf(acc[2] + bb.z); o.w = geluf(acc[3] + bb.w);
    *(float4*)&g_inter0[(size_t)m * 1024 + col] = o;
  }
}

// step-0 g2: cont0 = inter0 @ w2 (raw; b2 added in cellfull), K=1024 sequential
__global__ __launch_bounds__(512) void k_g2s(const float* __restrict__ w2) {
  __shared__ float As[64][33];
  __shared__ float Ws[64][68];
  const int tid = threadIdx.x;
  const int wgid = blockIdx.x;
  const int tsw = wgid >> 3;
  const int colB = ((wgid & 7) + 8 * (tsw & 1)) * 64;
  const int rowB = (tsw >> 1) * 32;
  const int row = tid & 31, cg = tid >> 5;
  const int ar = tid >> 4, ak = (tid & 15) * 4;
  int ms = rowB + ar; if (ms > kM0 - 1) ms = kM0 - 1;
  const float* Ab = g_inter0 + (size_t)ms * 1024;
  float4 aR = *(const float4*)&Ab[ak];
  float4 wR[2];
#pragma unroll
  for (int q = 0; q < 2; ++q) {
    int f = tid + q * 512; int kk = f >> 4, c4 = f & 15;
    wR[q] = *(const float4*)&w2[(size_t)kk * 1024 + colB + c4 * 4];
  }
  float acc[4] = {};
  for (int c = 0; c < 16; ++c) {
    As[ak + 0][ar] = aR.x; As[ak + 1][ar] = aR.y;
    As[ak + 2][ar] = aR.z; As[ak + 3][ar] = aR.w;
#pragma unroll
    for (int q = 0; q < 2; ++q) {
      int f = tid + q * 512; int kk = f >> 4, c4 = f & 15;
      *(float4*)&Ws[kk][c4 * 4] = wR[q];
    }
    __syncthreads();
    if (c < 15) {
      int kb = (c + 1) * 64;
      aR = *(const float4*)&Ab[kb + ak];
#pragma unroll
      for (int q = 0; q < 2; ++q) {
        int f = tid + q * 512; int kk = f >> 4, c4 = f & 15;
        wR[q] = *(const float4*)&w2[(size_t)(kb + kk) * 1024 + colB + c4 * 4];
      }
    }
#pragma unroll
    for (int kk = 0; kk < 64; ++kk) {
      float a = As[kk][row];
      float4 w = *(const float4*)&Ws[kk][cg * 4];
      acc[0] = fmaf(a, w.x, acc[0]); acc[1] = fmaf(a, w.y, acc[1]);
      acc[2] = fmaf(a, w.z, acc[2]); acc[3] = fmaf(a, w.w, acc[3]);
    }
    __syncthreads();
  }
  int m = rowB + row;
  int col = colB + cg * 4;
  if (m < kM0) {
    float4 o = {acc[0], acc[1], acc[2], acc[3]};
    *(float4*)&g_cont0[(size_t)m * 1024 + col] = o;
  }
}

// tail g2: partials over K-range [Ks*256, +256); A assembled as gelu(sum(p1)+b1)
__device__ __forceinline__ float4 g2t_loadA(int grow, int kpos, const float* __restrict__ b1) {
  size_t g = (size_t)grow * 1024 + kpos;
  float4 p0 = *(const float4*)&g_p1[0][g];
  float4 p1 = *(const float4*)&g_p1[1][g];
  float4 p2 = *(const float4*)&g_p1[2][g];
  float4 p3 = *(const float4*)&g_p1[3][g];
  float4 bb = *(const float4*)&b1[kpos];
  float4 r;
  r.x = geluf(p0.x + p1.x + p2.x + p3.x + bb.x);
  r.y = geluf(p0.y + p1.y + p2.y + p3.y + bb.y);
  r.z = geluf(p0.z + p1.z + p2.z + p3.z + bb.z);
  r.w = geluf(p0.w + p1.w + p2.w + p3.w + bb.w);
  return r;
}

__global__ __launch_bounds__(512) void k_g2t(const float* __restrict__ w2,
                                             const float* __restrict__ b1) {
  __shared__ float As[64][33];
  __shared__ float Ws[64][68];
  const int tid = threadIdx.x;
  const int colB = blockIdx.x * 64;
  const int rowB = blockIdx.y * 32;
  const int Ks = blockIdx.z;
  const int kb0 = Ks * 256;
  const int row = tid & 31, cg = tid >> 5;
  const int ar = tid >> 4, ak = (tid & 15) * 4;
  const int grow = rowB + ar;
  float4 aR = g2t_loadA(grow, kb0 + ak, b1);
  float4 wR[2];
#pragma unroll
  for (int q = 0; q < 2; ++q) {
    int f = tid + q * 512; int kk = f >> 4, c4 = f & 15;
    wR[q] = *(const float4*)&w2[(size_t)(kb0 + kk) * 1024 + colB + c4 * 4];
  }
  float acc[4] = {};
  for (int c = 0; c < 4; ++c) {
    As[ak + 0][ar] = aR.x; As[ak + 1][ar] = aR.y;
    As[ak + 2][ar] = aR.z; As[ak + 3][ar] = aR.w;
#pragma unroll
    for (int q = 0; q < 2; ++q) {
      int f = tid + q * 512; int kk = f >> 4, c4 = f & 15;
      *(float4*)&Ws[kk][c4 * 4] = wR[q];
    }
    __syncthreads();
    if (c < 3) {
      int kb = kb0 + (c + 1) * 64;
      aR = g2t_loadA(grow, kb + ak, b1);
#pragma unroll
      for (int q = 0; q < 2; ++q) {
        int f = tid + q * 512; int kk = f >> 4, c4 = f & 15;
        wR[q] = *(const float4*)&w2[(size_t)(kb + kk) * 1024 + colB + c4 * 4];
      }
    }
#pragma unroll
    for (int kk = 0; kk < 64; ++kk) {
      float a = As[kk][row];
      float4 w = *(const float4*)&Ws[kk][cg * 4];
      acc[0] = fmaf(a, w.x, acc[0]); acc[1] = fmaf(a, w.y, acc[1]);
      acc[2] = fmaf(a, w.z, acc[2]); acc[3] = fmaf(a, w.w, acc[3]);
    }
    __syncthreads();
  }
  int col = colB + cg * 4;
  float4 o = {acc[0], acc[1], acc[2], acc[3]};
  *(float4*)&g_p2[Ks][(rowB + row) * 1024 + col] = o;
}

// ---------------- step-0 cell (all 496 rows) ----------------
__global__ __launch_bounds__(256) void k_cellfull(const float* __restrict__ imask,
                                                  const float* __restrict__ ln2g,
                                                  const float* __restrict__ ln2b,
                                                  const float* __restrict__ decW,
                                                  const float* __restrict__ b2) {
  int m = blockIdx.x;    // n*31 + j
  int d = threadIdx.x;
  int n = m / 31, j = m - n * 31;
  const float* st = g_state[0] + (n * 4) * 8192;
  const float* crow = g_cont0 + (size_t)m * 1024;
  float c0 = crow[d] + b2[d];
  float c1 = crow[256 + d] + b2[256 + d];
  float c2 = crow[512 + d] + b2[512 + d];
  float c3 = crow[768 + d] + b2[768 + d];
  float l = st[j * 256 + d];
  float r = st[(j + 1) * 256 + d];
  float f1 = 1.0f / (1.0f + expf(-c0));
  float f2 = 1.0f / (1.0f + expf(-c1));
  float ig = 1.0f / (1.0f + expf(-c2));
  float pre = f1 * l + f2 * r + ig * c3;
  __shared__ float red4[4];
  __shared__ float w5[4][5];
  float mean = blockSum256(pre, red4, d) * (1.0f / 256.0f);
  float cen = pre - mean;
  float var = blockSum256(cen * cen, red4, d) * (1.0f / 256.0f);
  float nh = cen / sqrtf(var + 1e-5f) * ln2g[d] + ln2b[d];
  g_nh0[m * 256 + d] = nh;
  float mv = imask[n * 32 + 1 + j];
  float nhm = nh * mv;
  float pv[5];
#pragma unroll
  for (int t = 0; t < 5; ++t) pv[t] = nhm * decW[t * 256 + d];
#pragma unroll
  for (int t = 0; t < 5; ++t)
#pragma unroll
    for (int o = 32; o > 0; o >>= 1) pv[t] += __shfl_down(pv[t], o, 64);
  __syncthreads();
  if ((d & 63) == 0) {
#pragma unroll
    for (int t = 0; t < 5; ++t) w5[d >> 6][t] = pv[t];
  }
  __syncthreads();
  if (d < 5) g_s50[m * 5 + d] = w5[0][d] + w5[1][d] + w5[2][d] + w5[3][d];
}

// ---------------- fused cell(fresh) + decide + merge + next-step g1 partials ----------------
// grid (64, 8): grp 0..7.  Phase C: 1 row/wave (jrow = grp*4+wv).
// Phase D: my = grp>>2 selects output srow, Ks = grp&3 the K-split.
__global__ __launch_bounds__(256) void k_cm(
    const float* __restrict__ imask, const float* __restrict__ decW,
    const float* __restrict__ decb, const float* __restrict__ b2,
    const float* __restrict__ ln2g, const float* __restrict__ ln2b,
    const float* __restrict__ w1, int i, int last) {
  const int b = blockIdx.x, grp = blockIdx.y;
  const int tid = threadIdx.x, st = tid, lane = tid & 63, wv = tid >> 6;
  const int Sc = 31 - i;
  const int buf = i & 1;
  const int n32 = (b >> 2) * 32;
  __shared__ float sh_nhf[2][256];
  __shared__ float sh_s5f[2][5];
  __shared__ float sA[3][256];
  __shared__ float red4[4];
  __shared__ float w5s[4][5];
  __shared__ int sh_k;
  __shared__ float sh_sv;
  int slot0 = -1, slot1 = -1;
  if (i > 0) { slot0 = g_slots[buf][2 * b]; slot1 = g_slots[buf][2 * b + 1]; }
  const float* s5Src = (i == 0) ? (g_s50 + (b >> 2) * kP0 * 5) : (g_s5[buf] + b * kP0 * 5);
  const float* nhSrcG = (i == 0) ? (g_nh0 + (size_t)(b >> 2) * kP0 * 256)
                                 : (g_nh[buf] + (size_t)b * kP0 * 256);
  const float* stOld = g_state[buf] + b * 8192;
  float* stNew = g_state[(i + 1) & 1] + b * 8192;
  float* nhDst = g_nh[(i + 1) & 1] + (size_t)b * kP0 * 256;
  float* s5Dst = g_s5[(i + 1) & 1] + b * kP0 * 5;
  float done = imask[n32 + i + 1];

  // ---- phase A: fresh-row cell (redundant per WG of b; block-uniform branches) ----
  if (i > 0) {
#pragma unroll 1
    for (int s = 0; s < 2; ++s) {
      int j = (s == 0) ? slot0 : slot1;
      if (j < 0) continue;
      int sr = 2 * b + s;
      float c[4];
#pragma unroll
      for (int q = 0; q < 4; ++q) {
        int g = sr * 1024 + q * 256 + st;
        float v = ((g_p2[0][g] + g_p2[1][g]) + g_p2[2][g]) + g_p2[3][g];
        c[q] = v + b2[q * 256 + st];
      }
      float l = stOld[j * 256 + st];
      float r = stOld[(j + 1) * 256 + st];
      float f1 = 1.0f / (1.0f + expf(-c[0]));
      float f2 = 1.0f / (1.0f + expf(-c[1]));
      float ig = 1.0f / (1.0f + expf(-c[2]));
      float pre = f1 * l + f2 * r + ig * c[3];
      float mean = blockSum256(pre, red4, st) * (1.0f / 256.0f);
      float cen = pre - mean;
      float var = blockSum256(cen * cen, red4, st) * (1.0f / 256.0f);
      float nh = cen / sqrtf(var + 1e-5f) * ln2g[st] + ln2b[st];
      sh_nhf[s][st] = nh;
      float mv = imask[n32 + i + 1 + j];
      float nhm = nh * mv;
      float pv[5];
#pragma unroll
      for (int t = 0; t < 5; ++t) pv[t] = nhm * decW[t * 256 + st];
#pragma unroll
      for (int t = 0; t < 5; ++t) {
        float v = pv[t];
#pragma unroll
        for (int o = 32; o > 0; o >>= 1) v += __shfl_down(v, o, 64);
        pv[t] = v;
      }
      __syncthreads();
      if (lane == 0) {
#pragma unroll
        for (int t = 0; t < 5; ++t) w5s[wv][t] = pv[t];
      }
      __syncthreads();
      if (st < 5) sh_s5f[s][st] = w5s[0][st] + w5s[1][st] + w5s[2][st] + w5s[3][st];
    }
  }
  __syncthreads();

  // ---- phase B: decide (wave 0), bit-exact round-2 math ----
  if (!last && tid < 64) {
    int j = lane;
    bool act = j < Sc;
    float mv = 0.f, lg = 0.f;
    if (act) {
      mv = imask[n32 + i + 1 + j];
      float t5 = decb[0];
      if (j >= 2) {
        int rw = j - 2;
        t5 += (i > 0 && rw == slot0) ? sh_s5f[0][0] : (i > 0 && rw == slot1) ? sh_s5f[1][0] : s5Src[rw * 5 + 0];
      }
      if (j >= 1) {
        int rw = j - 1;
        t5 += (i > 0 && rw == slot0) ? sh_s5f[0][1] : (i > 0 && rw == slot1) ? sh_s5f[1][1] : s5Src[rw * 5 + 1];
      }
      {
        int rw = j;
        t5 += (i > 0 && rw == slot0) ? sh_s5f[0][2] : (i > 0 && rw == slot1) ? sh_s5f[1][2] : s5Src[rw * 5 + 2];
      }
      if (j + 1 < Sc) {
        int rw = j + 1;
        t5 += (i > 0 && rw == slot0) ? sh_s5f[0][3] : (i > 0 && rw == slot1) ? sh_s5f[1][3] : s5Src[rw * 5 + 3];
      }
      if (j + 2 < Sc) {
        int rw = j + 2;
        t5 += (i > 0 && rw == slot0) ? sh_s5f[0][4] : (i > 0 && rw == slot1) ? sh_s5f[1][4] : s5Src[rw * 5 + 4];
      }
      lg = t5 / 35.77708763999664f;
    }
    uint32_t fk0, fk1, o0, o1;
    tf2x32(0u, 1234u, 0u, (uint32_t)i, fk0, fk1);
    uint32_t idx = (uint32_t)(b * Sc + j);
    tf2x32(fk0, fk1, 0u, idx, o0, o1);
    uint32_t bits = o0 ^ o1;
    float u = __uint_as_float((bits >> 9) | 0x3f800000u) - 1.0f;
    float gum = -logf(-logf(u + 1e-20f) + 1e-20f);
    float z = lg + gum;
    float zm = waveMax64(act ? z : -3.0e38f);
    float e = act ? expf(z - zm) : 0.f;
    float p = e / waveSum64(e);
    float y = act ? (p * mv + 1e-20f) : 0.f;
    float ys = y / waveSum64(y);
    float av = act ? ys : -1.f;
    int ai = j;
#pragma unroll
    for (int o = 32; o > 0; o >>= 1) {
      float ov = __shfl_xor(av, o, 64);
      int oi = __shfl_xor(ai, o, 64);
      if (ov > av || (ov == av && oi < ai)) { av = ov; ai = oi; }
    }
    float lm = waveMax64(act ? lg : -3.0e38f);
    float e2 = act ? expf(lg - lm) : 0.f;
    float p2 = e2 / waveSum64(e2);
    float y2 = act ? (p2 * mv + 1e-20f) : 0.f;
    float ps = y2 / waveSum64(y2);
    float ysk = __shfl(ys, ai, 64);
    float psk = __shfl(ps, ai, 64);
    float sv = (1.0f - ysk) + ysk;
    if (j == 0) {
      sh_k = ai;
      sh_sv = sv;
      if (grp == 0) {
        g_accu[b] += done * logf(sv * psk + 1e-20f);
        int s0 = -1, s1 = -1;
        if (done != 0.0f) {
          if (ai >= 1) s0 = ai - 1;
          if (ai <= Sc - 2) s1 = ai;
        }
        g_slots[(i + 1) & 1][2 * b] = s0;
        g_slots[(i + 1) & 1][2 * b + 1] = s1;
      }
    }
  }
  __syncthreads();

  // ---- last step (i==30): no select, state -> single row ----
  if (last) {
    if (grp == 0 && wv == 0) {
      float4 ol = *(const float4*)&stOld[lane * 4];
      float4 nh4;
      if (slot0 == 0) nh4 = *(const float4*)&sh_nhf[0][lane * 4];
      else if (slot1 == 0) nh4 = *(const float4*)&sh_nhf[1][lane * 4];
      else nh4 = *(const float4*)&nhSrcG[lane * 4];
      float4 o4;
      o4.x = done * nh4.x + (1.0f - done) * ol.x;
      o4.y = done * nh4.y + (1.0f - done) * ol.y;
      o4.z = done * nh4.z + (1.0f - done) * ol.z;
      o4.w = done * nh4.w + (1.0f - done) * ol.w;
      *(float4*)&stNew[lane * 4] = o4;
    }
    return;
  }

  // ---- phase C: merge + shift (1 row per wave) ----
  int k = sh_k;
  float sv = sh_sv;
  {
    int jrow = grp * 4 + wv;
    if (jrow < Sc) {
      float4 ol = *(const float4*)&stOld[jrow * 256 + lane * 4];
      float4 ov4;
      if (done != 0.0f) {
        float4 mg;
        if (jrow < k) {
          mg = ol;
        } else if (jrow == k) {
          float4 nh4 = (i > 0 && k == slot0) ? *(const float4*)&sh_nhf[0][lane * 4]
                     : (i > 0 && k == slot1) ? *(const float4*)&sh_nhf[1][lane * 4]
                     : *(const float4*)&nhSrcG[k * 256 + lane * 4];
          mg.x = sv * nh4.x + (1.0f - sv) * ol.x;
          mg.y = sv * nh4.y + (1.0f - sv) * ol.y;
          mg.z = sv * nh4.z + (1.0f - sv) * ol.z;
          mg.w = sv * nh4.w + (1.0f - sv) * ol.w;
        } else {
          float4 orr = *(const float4*)&stOld[(jrow + 1) * 256 + lane * 4];
          mg.x = (1.0f - sv) * ol.x + sv * orr.x;
          mg.y = (1.0f - sv) * ol.y + sv * orr.y;
          mg.z = (1.0f - sv) * ol.z + sv * orr.z;
          mg.w = (1.0f - sv) * ol.w + sv * orr.w;
        }
        ov4.x = done * mg.x + (1.0f - done) * ol.x;
        ov4.y = done * mg.y + (1.0f - done) * ol.y;
        ov4.z = done * mg.z + (1.0f - done) * ol.z;
        ov4.w = done * mg.w + (1.0f - done) * ol.w;
      } else {
        ov4 = ol;
      }
      *(float4*)&stNew[jrow * 256 + lane * 4] = ov4;
      if (jrow < Sc - 1) {
        int src = (done != 0.0f && jrow > k) ? jrow + 1 : jrow;
        float4 nv = (i > 0 && src == slot0) ? *(const float4*)&sh_nhf[0][lane * 4]
                  : (i > 0 && src == slot1) ? *(const float4*)&sh_nhf[1][lane * 4]
                  : *(const float4*)&nhSrcG[src * 256 + lane * 4];
        *(float4*)&nhDst[jrow * 256 + lane * 4] = nv;
        float mv2 = imask[n32 + i + 2 + jrow];
        float pv[5];
#pragma unroll
        for (int t = 0; t < 5; ++t) {
          const float* dw = decW + t * 256 + lane * 4;
          pv[t] = (nv.x * dw[0] + nv.y * dw[1] + nv.z * dw[2] + nv.w * dw[3]) * mv2;
        }
#pragma unroll
        for (int t = 0; t < 5; ++t) {
          float v = pv[t];
#pragma unroll
          for (int o = 32; o > 0; o >>= 1) v += __shfl_down(v, o, 64);
          pv[t] = v;
        }
        if (lane == 0) {
#pragma unroll
          for (int t = 0; t < 5; ++t) s5Dst[jrow * 5 + t] = pv[t];
        }
      }
    }
  }

  // ---- phase D: next-step g1 split-K partial (my = grp>>2 srow, Ks = grp&3) ----
  if (done != 0.0f) {
    __syncthreads();
    {
      int d = st;
      float nhKv = (i > 0 && k == slot0) ? sh_nhf[0][d]
                 : (i > 0 && k == slot1) ? sh_nhf[1][d]
                 : nhSrcG[k * 256 + d];
#pragma unroll
      for (int t = 0; t < 3; ++t) {
        int r = k - 1 + t;
        if (r < 0 || r > Sc - 1) continue;
        float ol = stOld[r * 256 + d];
        float mg;
        if (r < k) mg = ol;
        else if (r == k) mg = sv * nhKv + (1.0f - sv) * ol;
        else mg = (1.0f - sv) * ol + sv * stOld[(r + 1) * 256 + d];
        sA[t][d] = done * mg + (1.0f - done) * ol;
      }
    }
    __syncthreads();
    const int my = grp >> 2;
    const int Ks = grp & 3;
    const int has = (my == 0) ? (k >= 1) : (k <= Sc - 2);
    const int kb0 = Ks * 128;
    const float* A = (my == 0) ? ((Ks < 2) ? sA[0] : sA[1])
                               : ((Ks < 2) ? sA[1] : sA[2]);
    const int koff = (Ks < 2) ? kb0 : (kb0 - 256);
    const int col = st * 4;
    float a0 = 0.f, a1 = 0.f, a2 = 0.f, a3 = 0.f;
    for (int kk = 0; kk < 128; ++kk) {
      float4 w = *(const float4*)&w1[(size_t)(kb0 + kk) * 1024 + col];
      float av = A[koff + kk];
      a0 = fmaf(av, w.x, a0); a1 = fmaf(av, w.y, a1);
      a2 = fmaf(av, w.z, a2); a3 = fmaf(av, w.w, a3);
    }
    if (has) {
      float4 o = {a0, a1, a2, a3};
      *(float4*)&g_p1[Ks][(2 * b + my) * 1024 + col] = o;
    }
  }
}

// ---------------- final weighted sum over B ----------------
__global__ __launch_bounds__(256) void k_final(float* __restrict__ out) {
  int n = blockIdx.x, d = threadIdx.x;
  float a0 = g_accu[n * 4 + 0], a1 = g_accu[n * 4 + 1];
  float a2 = g_accu[n * 4 + 2], a3 = g_accu[n * 4 + 3];
  float mx = fmaxf(fmaxf(a0, a1), fmaxf(a2, a3));
  float e0 = expf(a0 - mx), e1 = expf(a1 - mx), e2 = expf(a2 - mx), e3 = expf(a3 - mx);
  float ssum = e0 + e1 + e2 + e3;
  const float* st1 = g_state[1];
  float h0 = st1[(n * 4 + 0) * 8192 + d];
  float h1 = st1[(n * 4 + 1) * 8192 + d];
  float h2 = st1[(n * 4 + 2) * 8192 + d];
  float h3 = st1[(n * 4 + 3) * 8192 + d];
  out[n * 256 + d] = (e0 / ssum) * h0 + (e1 / ssum) * h1 + (e2 / ssum) * h2 + (e3 / ssum) * h3;
}

extern "C" void kernel_launch(void* const* d_in, const int* in_sizes, int n_in,
                              void* d_out, int out_size, void* d_ws, size_t ws_size,
                              hipStream_t stream) {
  (void)in_sizes; (void)n_in; (void)d_ws; (void)ws_size; (void)out_size;
  const float* x = (const float*)d_in[0];
  const float* imask = (const float*)d_in[1];
  const float* wW = (const float*)d_in[2];
  const float* wb = (const float*)d_in[3];
  const float* lng = (const float*)d_in[4];
  const float* lnb = (const float*)d_in[5];
  const float* w1 = (const float*)d_in[6];
  const float* b1 = (const float*)d_in[7];
  const float* w2 = (const float*)d_in[8];
  const float* b2 = (const float*)d_in[9];
  const float* ln2g = (const float*)d_in[10];
  const float* ln2b = (const float*)d_in[11];
  const float* decW = (const float*)d_in[12];
  const float* decb = (const float*)d_in[13];
  float* out = (float*)d_out;

  k_embed<<<dim3(512), dim3(256), 0, stream>>>(x, wW, wb, lng, lnb);
  k_g1s<<<dim3(256), dim3(512), 0, stream>>>(w1, b1);
  k_g2s<<<dim3(256), dim3(512), 0, stream>>>(w2);
  k_cellfull<<<dim3(kM0), dim3(256), 0, stream>>>(imask, ln2g, ln2b, decW, b2);
  k_cm<<<dim3(64, 8), dim3(256), 0, stream>>>(imask, decW, decb, b2, ln2g, ln2b, w1, 0, 0);
  for (int i = 1; i <= 30; ++i) {
    k_g2t<<<dim3(16, 4, 4), dim3(512), 0, stream>>>(w2, b1);
    int lastf = (i == 30) ? 1 : 0;
    k_cm<<<dim3(64, lastf ? 1 : 8), dim3(256), 0, stream>>>(imask, decW, decb, b2,
                                                            ln2g, ln2b, w1, i, lastf);
  }
  k_final<<<dim3(16), dim3(256), 0, stream>>>(out);
}